// Round 5
// baseline (3063.906 us; speedup 1.0000x reference)
//
#include <hip/hip_runtime.h>
#include <hip/hip_bf16.h>
#include <math.h>

#define B_ 16
#define S_ 256
#define T_ 800
#define V_ 256
#define D_ 512
#define M_ 80
#define H_ 1024
#define NH_ 4
#define HD_ 128
#define EH_ 256

using bf16x8 = __attribute__((ext_vector_type(8))) short;
using f32x4  = __attribute__((ext_vector_type(4))) float;
typedef _Float16 half8 __attribute__((ext_vector_type(8)));

__device__ __forceinline__ float sigf(float x) { return 1.f / (1.f + __expf(-x)); }
__device__ __forceinline__ float tanhfast(float x) {
    float e = __expf(2.f * x);
    return 1.f - 2.f / (e + 1.f);
}

__device__ __forceinline__ unsigned short f2bf(float f) {
    unsigned int u = __float_as_uint(f);
    unsigned int r = (u + 0x7FFFu + ((u >> 16) & 1u)) >> 16;
    return (unsigned short)r;
}

__device__ __forceinline__ void gl_lds16(const unsigned short* g, unsigned short* l) {
    __builtin_amdgcn_global_load_lds((const __attribute__((address_space(1))) void*)g,
                                     (__attribute__((address_space(3))) void*)l, 16, 0, 0);
}

// ---------------- MFMA bf16 GEMM: C = A(M,K) @ B(N,K)^T --------------------
// epi: 0 fp32 out(+bias), 1 conv BN+ReLU fp32, 2 bf16 out(+bias), 3 v^T bf16 store
__global__ __launch_bounds__(256) void gemm_mfma(
    const unsigned short* __restrict__ A, const unsigned short* __restrict__ Bw,
    void* __restrict__ Cv, const float* __restrict__ bias,
    int M, int N, int K, int ldc, int epi,
    const float* __restrict__ cb, const float* __restrict__ gam,
    const float* __restrict__ bet, const float* __restrict__ mu,
    const float* __restrict__ va)
{
    __shared__ unsigned short As[4096];
    __shared__ unsigned short Bs[4096];
    const int tid = threadIdx.x, w = tid >> 6, lane = tid & 63;
    const int bm = blockIdx.y * 128, bn = blockIdx.x * 128;
    const int wr = w >> 1, wc = w & 1;

    f32x4 acc[4][4];
#pragma unroll
    for (int m = 0; m < 4; ++m)
#pragma unroll
        for (int n = 0; n < 4; ++n) acc[m][n] = (f32x4){0.f, 0.f, 0.f, 0.f};

    const int r0 = w * 16 + (lane >> 2);
    const int k8 = (lane & 3) * 8;
    const unsigned short* Ag = A + (size_t)(bm + r0) * K + k8;
    const unsigned short* Bg = Bw + (size_t)(bn + r0) * K + k8;
    unsigned short* Al = As + w * 512;
    unsigned short* Bl = Bs + w * 512;

    for (int k0 = 0; k0 < K; k0 += 32) {
        __syncthreads();
        gl_lds16(Ag + k0, Al);
        gl_lds16(Ag + (size_t)64 * K + k0, Al + 2048);
        gl_lds16(Bg + k0, Bl);
        gl_lds16(Bg + (size_t)64 * K + k0, Bl + 2048);
        __syncthreads();
        bf16x8 a[4], b[4];
#pragma unroll
        for (int m = 0; m < 4; ++m)
            a[m] = *(const bf16x8*)(As + (wr * 64 + m * 16 + (lane & 15)) * 32 + (lane >> 4) * 8);
#pragma unroll
        for (int n = 0; n < 4; ++n)
            b[n] = *(const bf16x8*)(Bs + (wc * 64 + n * 16 + (lane & 15)) * 32 + (lane >> 4) * 8);
#pragma unroll
        for (int m = 0; m < 4; ++m)
#pragma unroll
            for (int n = 0; n < 4; ++n)
                acc[m][n] = __builtin_amdgcn_mfma_f32_16x16x32_bf16(a[m], b[n], acc[m][n], 0, 0, 0);
    }

    const int cr = (lane >> 4) * 4, ccol = lane & 15;
#pragma unroll
    for (int m = 0; m < 4; ++m)
#pragma unroll
        for (int n = 0; n < 4; ++n) {
            const int col = bn + wc * 64 + n * 16 + ccol;
            const float bv = bias ? bias[col] : 0.f;
#pragma unroll
            for (int j = 0; j < 4; ++j) {
                const int row = bm + wr * 64 + m * 16 + cr + j;
                float v = acc[m][n][j] + bv;
                if (epi == 1) {
                    float x = v + cb[col];
                    v = fmaxf(0.f, gam[col] * (x - mu[col]) * rsqrtf(va[col] + 1e-5f) + bet[col]);
                }
                if (epi == 2) {
                    ((unsigned short*)Cv)[(size_t)row * ldc + col] = f2bf(v);
                } else if (epi == 3) {
                    const int bb2 = row >> 8, ss = row & 255, hh = col >> 7, dd = col & 127;
                    ((unsigned short*)Cv)[((size_t)(bb2 * 4 + hh) * 128 + dd) * 256 + ss] = f2bf(v);
                } else {
                    ((float*)Cv)[(size_t)row * ldc + col] = v;
                }
            }
        }
}

// ---------------- attention QK^T (per b,h): scores = q @ k^T * scale -------
__global__ __launch_bounds__(256) void attn_qk(
    const unsigned short* __restrict__ q, const unsigned short* __restrict__ k,
    float* __restrict__ scores)
{
    __shared__ unsigned short As[4096];
    __shared__ unsigned short Bs[4096];
    const int tid = threadIdx.x, w = tid >> 6, lane = tid & 63;
    const int bm = blockIdx.y * 128, bn = blockIdx.x * 128;
    const int z = blockIdx.z, b = z >> 2, h = z & 3;
    const int wr = w >> 1, wc = w & 1;

    const unsigned short* A  = q + ((size_t)b * T_) * 512 + h * 128;
    const unsigned short* Bw = k + ((size_t)b * S_) * 512 + h * 128;

    f32x4 acc[4][4];
#pragma unroll
    for (int m = 0; m < 4; ++m)
#pragma unroll
        for (int n = 0; n < 4; ++n) acc[m][n] = (f32x4){0.f, 0.f, 0.f, 0.f};

    const int r0 = w * 16 + (lane >> 2);
    const int k8 = (lane & 3) * 8;
    const unsigned short* Ag = A + (size_t)(bm + r0) * 512 + k8;
    const unsigned short* Bg = Bw + (size_t)(bn + r0) * 512 + k8;
    unsigned short* Al = As + w * 512;
    unsigned short* Bl = Bs + w * 512;

    for (int k0 = 0; k0 < 128; k0 += 32) {
        __syncthreads();
        gl_lds16(Ag + k0, Al);
        gl_lds16(Ag + (size_t)64 * 512 + k0, Al + 2048);
        gl_lds16(Bg + k0, Bl);
        gl_lds16(Bg + (size_t)64 * 512 + k0, Bl + 2048);
        __syncthreads();
        bf16x8 a[4], bfr[4];
#pragma unroll
        for (int m = 0; m < 4; ++m)
            a[m] = *(const bf16x8*)(As + (wr * 64 + m * 16 + (lane & 15)) * 32 + (lane >> 4) * 8);
#pragma unroll
        for (int n = 0; n < 4; ++n)
            bfr[n] = *(const bf16x8*)(Bs + (wc * 64 + n * 16 + (lane & 15)) * 32 + (lane >> 4) * 8);
#pragma unroll
        for (int m = 0; m < 4; ++m)
#pragma unroll
            for (int n = 0; n < 4; ++n)
                acc[m][n] = __builtin_amdgcn_mfma_f32_16x16x32_bf16(a[m], bfr[n], acc[m][n], 0, 0, 0);
    }

    const int cr = (lane >> 4) * 4, ccol = lane & 15;
#pragma unroll
    for (int m = 0; m < 4; ++m)
#pragma unroll
        for (int n = 0; n < 4; ++n) {
            const int col = bn + wc * 64 + n * 16 + ccol;
#pragma unroll
            for (int j = 0; j < 4; ++j) {
                const int row = bm + wr * 64 + m * 16 + cr + j;
                if (row < T_)
                    scores[((size_t)z * T_ + row) * 256 + col] = acc[m][n][j] * 0.08838834764831843f;
            }
        }
}

// ---------------- softmax over s (wave per row) ----------------------------
__global__ __launch_bounds__(256) void attn_sm(
    const float* __restrict__ scores, unsigned short* __restrict__ probs)
{
    const int row = blockIdx.x * 4 + (threadIdx.x >> 6);
    const int lane = threadIdx.x & 63;
    const float4 v = *(const float4*)(scores + (size_t)row * 256 + lane * 4);
    float m = fmaxf(fmaxf(v.x, v.y), fmaxf(v.z, v.w));
    for (int off = 32; off; off >>= 1) m = fmaxf(m, __shfl_xor(m, off));
    float ex = __expf(v.x - m), ey = __expf(v.y - m), ez = __expf(v.z - m), ew = __expf(v.w - m);
    float sum = ex + ey + ez + ew;
    for (int off = 32; off; off >>= 1) sum += __shfl_xor(sum, off);
    const float inv = 1.f / sum;
    ushort4 o;
    o.x = f2bf(ex * inv); o.y = f2bf(ey * inv); o.z = f2bf(ez * inv); o.w = f2bf(ew * inv);
    *(ushort4*)(probs + (size_t)row * 256 + lane * 4) = o;
}

// ---------------- attention PV (per b,h): ctx = probs @ vT^T ---------------
__global__ __launch_bounds__(256) void attn_pv(
    const unsigned short* __restrict__ probs, const unsigned short* __restrict__ vT,
    unsigned short* __restrict__ ctx)
{
    __shared__ unsigned short As[4096];
    __shared__ unsigned short Bs[4096];
    const int tid = threadIdx.x, w = tid >> 6, lane = tid & 63;
    const int bm = blockIdx.y * 128;
    const int z = blockIdx.z, b = z >> 2, h = z & 3;
    const int wr = w >> 1, wc = w & 1;

    const unsigned short* A  = probs + (size_t)z * T_ * 256;
    const unsigned short* Bw = vT + (size_t)z * 128 * 256;

    f32x4 acc[4][4];
#pragma unroll
    for (int m = 0; m < 4; ++m)
#pragma unroll
        for (int n = 0; n < 4; ++n) acc[m][n] = (f32x4){0.f, 0.f, 0.f, 0.f};

    const int r0 = w * 16 + (lane >> 2);
    const int k8 = (lane & 3) * 8;
    const unsigned short* Ag = A + (size_t)(bm + r0) * 256 + k8;
    const unsigned short* Bg = Bw + (size_t)r0 * 256 + k8;
    unsigned short* Al = As + w * 512;
    unsigned short* Bl = Bs + w * 512;

    for (int k0 = 0; k0 < 256; k0 += 32) {
        __syncthreads();
        gl_lds16(Ag + k0, Al);
        gl_lds16(Ag + (size_t)64 * 256 + k0, Al + 2048);
        gl_lds16(Bg + k0, Bl);
        gl_lds16(Bg + (size_t)64 * 256 + k0, Bl + 2048);
        __syncthreads();
        bf16x8 a[4], bfr[4];
#pragma unroll
        for (int m = 0; m < 4; ++m)
            a[m] = *(const bf16x8*)(As + (wr * 64 + m * 16 + (lane & 15)) * 32 + (lane >> 4) * 8);
#pragma unroll
        for (int n = 0; n < 4; ++n)
            bfr[n] = *(const bf16x8*)(Bs + (wc * 64 + n * 16 + (lane & 15)) * 32 + (lane >> 4) * 8);
#pragma unroll
        for (int m = 0; m < 4; ++m)
#pragma unroll
            for (int n = 0; n < 4; ++n)
                acc[m][n] = __builtin_amdgcn_mfma_f32_16x16x32_bf16(a[m], bfr[n], acc[m][n], 0, 0, 0);
    }

    const int cr = (lane >> 4) * 4, ccol = lane & 15;
#pragma unroll
    for (int m = 0; m < 4; ++m)
#pragma unroll
        for (int n = 0; n < 4; ++n) {
            const int col = wc * 64 + n * 16 + ccol;   // d in [0,128)
#pragma unroll
            for (int j = 0; j < 4; ++j) {
                const int row = bm + wr * 64 + m * 16 + cr + j;
                if (row < T_)
                    ctx[((size_t)b * T_ + row) * 512 + h * 128 + col] = f2bf(acc[m][n][j]);
            }
        }
}

// ---------------- fp32 tiled GEMM (mel head, N=80) --------------------------
__global__ __launch_bounds__(256) void gemm_tile(
    const float* __restrict__ A, int lda,
    const float* __restrict__ Bw,
    const float* __restrict__ bias,
    float* __restrict__ C, int ldc,
    int M, int N, int K)
{
    __shared__ float As[16][68];
    __shared__ float Bs[16][68];
    const int tid = threadIdx.x;
    const int bm = blockIdx.y * 64, bn = blockIdx.x * 64;
    const int tx = tid & 15, ty = tid >> 4;
    const int lr = tid >> 2, lk = (tid & 3) * 4;

    float acc[4][4] = {};

    const float* Aptr = A + (size_t)(bm + lr) * lda + lk;
    const bool bvalid = (bn + lr) < N;
    const float* Bptr = Bw + (size_t)(bvalid ? (bn + lr) : 0) * K + lk;

    for (int k0 = 0; k0 < K; k0 += 16) {
        float4 av = *(const float4*)(Aptr + k0);
        float4 bw = bvalid ? *(const float4*)(Bptr + k0) : make_float4(0.f, 0.f, 0.f, 0.f);
        As[lk + 0][lr] = av.x; As[lk + 1][lr] = av.y; As[lk + 2][lr] = av.z; As[lk + 3][lr] = av.w;
        Bs[lk + 0][lr] = bw.x; Bs[lk + 1][lr] = bw.y; Bs[lk + 2][lr] = bw.z; Bs[lk + 3][lr] = bw.w;
        __syncthreads();
#pragma unroll
        for (int k = 0; k < 16; ++k) {
            float4 a = *(const float4*)&As[k][ty * 4];
            float4 b = *(const float4*)&Bs[k][tx * 4];
            acc[0][0] += a.x * b.x; acc[0][1] += a.x * b.y; acc[0][2] += a.x * b.z; acc[0][3] += a.x * b.w;
            acc[1][0] += a.y * b.x; acc[1][1] += a.y * b.y; acc[1][2] += a.y * b.z; acc[1][3] += a.y * b.w;
            acc[2][0] += a.z * b.x; acc[2][1] += a.z * b.y; acc[2][2] += a.z * b.z; acc[2][3] += a.z * b.w;
            acc[3][0] += a.w * b.x; acc[3][1] += a.w * b.y; acc[3][2] += a.w * b.z; acc[3][3] += a.w * b.w;
        }
        __syncthreads();
    }

    const int row0 = bm + ty * 4, col0 = bn + tx * 4;
#pragma unroll
    for (int i = 0; i < 4; ++i)
#pragma unroll
        for (int j = 0; j < 4; ++j) {
            int cc = col0 + j;
            if (cc < N) {
                float v = acc[i][j];
                if (bias) v += bias[cc];
                C[(size_t)(row0 + i) * ldc + cc] = v;
            }
        }
}

// ---------------- elementwise / conversion kernels -------------------------
__global__ void embed_k(const int* __restrict__ txt, const float* __restrict__ emb,
                        float* __restrict__ xs)
{
    int idx = blockIdx.x * 256 + threadIdx.x;
    if (idx >= B_ * S_ * D_) return;
    int bs = idx >> 9, dd = idx & 511;
    xs[idx] = emb[(size_t)txt[bs] * D_ + dd];
}

__global__ void im2col_bf(const float* __restrict__ in, unsigned short* __restrict__ out)
{
    int idx = blockIdx.x * 256 + threadIdx.x;
    if (idx >= B_ * S_ * 2560) return;
    int r = idx / 2560, cc = idx % 2560;
    int din = cc / 5, kk = cc % 5;
    int b = r >> 8, s = r & 255;
    int sp = s + kk - 2;
    float v = (sp >= 0 && sp < S_) ? in[((size_t)b * S_ + sp) * D_ + din] : 0.f;
    out[idx] = f2bf(v);
}

__global__ void transp_bf(const float* __restrict__ in, unsigned short* __restrict__ out)
{
    int idx = blockIdx.x * 256 + threadIdx.x;
    if (idx >= B_ * S_ * D_) return;
    int d = idx & 511;
    int sb = idx >> 9;
    int s = sb >> 4, b = sb & 15;
    out[idx] = f2bf(in[((size_t)b * S_ + s) * D_ + d]);
}

__global__ void cvt_bf(const float* __restrict__ in, unsigned short* __restrict__ out,
                       int rows, int Kin, int Kout)
{
    int idx = blockIdx.x * 256 + threadIdx.x;
    if (idx >= rows * Kout) return;
    int r = idx / Kout, k = idx - r * Kout;
    out[idx] = (k < Kin) ? f2bf(in[(size_t)r * Kin + k]) : 0;
}

__global__ void cvt_w1(const float* __restrict__ W, unsigned short* __restrict__ out)
{
    int idx = blockIdx.x * 256 + threadIdx.x;
    if (idx >= 3072 * 608) return;
    int n = idx / 608, k = idx - n * 608;
    int orig = (n < 1024) ? n : n + 1024;
    out[idx] = (k < 592) ? f2bf(W[(size_t)orig * 592 + k]) : 0;
}

__global__ void cvt_w2(const float* __restrict__ W, unsigned short* __restrict__ out)
{
    int idx = blockIdx.x * 256 + threadIdx.x;
    if (idx >= 3072 * 1024) return;
    int n = idx >> 10, k = idx & 1023;
    int orig = (n < 1024) ? n : n + 1024;
    out[idx] = f2bf(W[(size_t)orig * 1024 + k]);
}

__global__ void decin_k2(const float* __restrict__ mel, unsigned short* __restrict__ din,
                         unsigned short* __restrict__ xcat)
{
    int idx = blockIdx.x * 256 + threadIdx.x;
    if (idx >= B_ * T_ * 96) return;
    int r = idx / 96, j = idx - r * 96;
    int b = r / T_, t = r - b * T_;
    float v = (j < M_ && t > 0) ? mel[((size_t)b * T_ + t - 1) * M_ + j] : 0.f;
    unsigned short bv = f2bf(v);
    din[(size_t)r * 96 + j] = bv;
    xcat[(size_t)r * 608 + 512 + j] = bv;
}

__global__ void dec_cell1(const float* __restrict__ g, const float* __restrict__ b1,
                          unsigned short* __restrict__ h, int rows)
{
    int idx = blockIdx.x * 256 + threadIdx.x;
    if (idx >= rows * H_) return;
    int r = idx >> 10, j = idx & 1023;
    const float* gr = g + (size_t)r * 3072;
    float ig = sigf(gr[j] + b1[j]);
    float gg = tanhfast(gr[1024 + j] + b1[2048 + j]);
    float og = sigf(gr[2048 + j] + b1[3072 + j]);
    h[idx] = f2bf(og * tanhfast(ig * gg));
}

__global__ void dec_cell2(const float* __restrict__ g, const float* __restrict__ b2,
                          float* __restrict__ h, int rows)
{
    int idx = blockIdx.x * 256 + threadIdx.x;
    if (idx >= rows * H_) return;
    int r = idx >> 10, j = idx & 1023;
    const float* gr = g + (size_t)r * 3072;
    float ig = sigf(gr[j] + b2[j]);
    float gg = tanhfast(gr[1024 + j] + b2[2048 + j]);
    float og = sigf(gr[2048 + j] + b2[3072 + j]);
    h[idx] = og * tanhfast(ig * gg);
}

__global__ __launch_bounds__(256) void stop_head(
    const float* __restrict__ h2, const float* __restrict__ sw,
    const float* __restrict__ sb, float* __restrict__ out)
{
    int row = blockIdx.x * 4 + (threadIdx.x >> 6);
    int lane = threadIdx.x & 63;
    const float* hr = h2 + (size_t)row * H_;
    float acc = 0.f;
#pragma unroll
    for (int i = 0; i < H_; i += 64) acc += hr[i + lane] * sw[i + lane];
    for (int off = 32; off; off >>= 1) acc += __shfl_xor(acc, off);
    if (lane == 0) out[row] = acc + sb[0];
}

// ---------------- persistent LSTM: 2 blocks per direction ------------------
// __launch_bounds__(1024, 4): 16 waves/block = 4 waves/SIMD -> VGPR cap 128,
// so the 64 VGPRs of weight fragments stay register-resident (r4 spilled at
// the compiler's default 64-reg choice).
// Sync: one-way per-step flags (release store / acquire poll), no RMW.
__global__ __launch_bounds__(1024, 4) void lstm_persist3(
    const float* __restrict__ gi_f, const float* __restrict__ gi_b,
    const float* __restrict__ Wf, const float* __restrict__ Wb,
    unsigned short* __restrict__ enc,     // bf16 (B,S,512)
    _Float16* __restrict__ hstage,        // [2][16][256]
    int* __restrict__ flags)              // [2][2][256]
{
    const int blk = blockIdx.x;
    const int dir = blk >> 1, half = blk & 1;
    const float* gi = dir ? gi_b : gi_f;
    const float* W  = dir ? Wb : Wf;
    const int tid = threadIdx.x, wv = tid >> 6, lane = tid & 63;
    const int l15 = lane & 15, q = lane >> 4;

    __shared__ _Float16 h_lds[16][264];   // [batch][hid 0..255], pad 8
    __shared__ float exch[512][17];       // [gate*128+hid_local][batch], pad 1

    // --- preload W fragments: wave wv owns tiles wv and wv+16 ---
    half8 w0[8], w1[8];
    {
        const int gt0 = wv >> 3, hb0 = wv & 7;          // tile wv
        const int gt1 = (wv + 16) >> 3;                 // tile wv+16 (same hb)
        const float* wr0 = W + (size_t)(gt0 * 256 + half * 128 + hb0 * 16 + l15) * 256;
        const float* wr1 = W + (size_t)(gt1 * 256 + half * 128 + hb0 * 16 + l15) * 256;
#pragma unroll
        for (int ks = 0; ks < 8; ++ks) {
            half8 a, b;
#pragma unroll
            for (int j = 0; j < 8; ++j) {
                a[j] = (_Float16)wr0[ks * 32 + q * 8 + j];
                b[j] = (_Float16)wr1[ks * 32 + q * 8 + j];
            }
            w0[ks] = a; w1[ks] = b;
        }
    }
    for (int i = tid; i < 16 * 264; i += 1024) ((_Float16*)h_lds)[i] = (_Float16)0.f;

    const int hid = tid & 127;
    const int ba  = tid >> 7;       // 0..7
    const int bb  = ba + 8;
    const int gh  = half * 128 + hid;
    float c0 = 0.f, c1 = 0.f;

    const int exr0 = (wv >> 3) * 128 + (wv & 7) * 16 + l15;
    const int exr1 = ((wv + 16) >> 3) * 128 + (wv & 7) * 16 + l15;

    const int pb = tid >> 6;                    // batch 0..15
    const int px = (half ^ 1) * 128 + (tid & 63) * 2;

    int* myflag = flags + (dir * 2 + half) * 256;
    int* pflag  = flags + (dir * 2 + (half ^ 1)) * 256;

    // gi prefetch for step 0
    float gp0[4], gp1[4];
    {
        const int s0 = dir ? 255 : 0;
        const float* g0 = gi + ((size_t)s0 * 16 + ba) * 1024 + gh;
        const float* g1 = gi + ((size_t)s0 * 16 + bb) * 1024 + gh;
#pragma unroll
        for (int g2 = 0; g2 < 4; ++g2) { gp0[g2] = g0[g2 * 256]; gp1[g2] = g1[g2 * 256]; }
    }
    __syncthreads();

    for (int step = 0; step < 256; ++step) {
        const int s = dir ? (255 - step) : step;

        f32x4 acc0 = (f32x4){0.f, 0.f, 0.f, 0.f};
        f32x4 acc1 = (f32x4){0.f, 0.f, 0.f, 0.f};
#pragma unroll
        for (int ks = 0; ks < 8; ++ks) {
            half8 a = *(const half8*)&h_lds[l15][ks * 32 + q * 8];
            acc0 = __builtin_amdgcn_mfma_f32_16x16x32_f16(a, w0[ks], acc0, 0, 0, 0);
            acc1 = __builtin_amdgcn_mfma_f32_16x16x32_f16(a, w1[ks], acc1, 0, 0, 0);
        }
        *(f32x4*)&exch[exr0][q * 4] = acc0;
        *(f32x4*)&exch[exr1][q * 4] = acc1;
        __syncthreads();

        // ---- c/h update: 2 (hid,batch) pairs per thread ----
        float h0, h1;
        {
            float xi = exch[hid][ba] + gp0[0];
            float xf = exch[128 + hid][ba] + gp0[1];
            float xg = exch[256 + hid][ba] + gp0[2];
            float xo = exch[384 + hid][ba] + gp0[3];
            float ig = sigf(xi), fg = sigf(xf), gg = tanhfast(xg), og = sigf(xo);
            c0 = fg * c0 + ig * gg; h0 = og * tanhfast(c0);
            xi = exch[hid][bb] + gp1[0];
            xf = exch[128 + hid][bb] + gp1[1];
            xg = exch[256 + hid][bb] + gp1[2];
            xo = exch[384 + hid][bb] + gp1[3];
            ig = sigf(xi); fg = sigf(xf); gg = tanhfast(xg); og = sigf(xo);
            c1 = fg * c1 + ig * gg; h1 = og * tanhfast(c1);
        }
        h_lds[ba][gh] = (_Float16)h0;
        h_lds[bb][gh] = (_Float16)h1;
        hstage[((size_t)dir * 16 + ba) * 256 + gh] = (_Float16)h0;
        hstage[((size_t)dir * 16 + bb) * 256 + gh] = (_Float16)h1;

        // all waves' hstage stores drained (vmcnt(0) before s_barrier)
        __syncthreads();
        if (tid == 0)
            __hip_atomic_store(&myflag[step], 1, __ATOMIC_RELEASE, __HIP_MEMORY_SCOPE_AGENT);

        // ---- overlap with partner wait: enc stores + next-step gi prefetch ----
        enc[((size_t)ba * S_ + s) * 512 + dir * 256 + gh] = f2bf(h0);
        enc[((size_t)bb * S_ + s) * 512 + dir * 256 + gh] = f2bf(h1);
        if (step < 255) {
            const int s2 = dir ? (254 - step) : (step + 1);
            const float* g0 = gi + ((size_t)s2 * 16 + ba) * 1024 + gh;
            const float* g1 = gi + ((size_t)s2 * 16 + bb) * 1024 + gh;
#pragma unroll
            for (int g2 = 0; g2 < 4; ++g2) { gp0[g2] = g0[g2 * 256]; gp1[g2] = g1[g2 * 256]; }
        }

        if (tid == 0)
            while (__hip_atomic_load(&pflag[step], __ATOMIC_ACQUIRE, __HIP_MEMORY_SCOPE_AGENT) == 0)
                __builtin_amdgcn_s_sleep(1);
        __syncthreads();
        __threadfence();
        // ---- read partner half into LDS ----
        {
            unsigned int v2 = *(const unsigned int*)&hstage[((size_t)dir * 16 + pb) * 256 + px];
            *(unsigned int*)&h_lds[pb][px] = v2;
        }
        __syncthreads();
    }
}

// ---------------- host orchestration --------------------------------------
static inline void launch_mfma(hipStream_t st, const unsigned short* A, const unsigned short* B,
                               void* C, const float* bias, int M, int N, int K, int ldc, int epi = 0,
                               const float* cb = nullptr, const float* gam = nullptr,
                               const float* bet = nullptr, const float* mu = nullptr,
                               const float* va = nullptr)
{
    dim3 grid(N / 128, M / 128);
    gemm_mfma<<<grid, 256, 0, st>>>(A, B, C, bias, M, N, K, ldc, epi, cb, gam, bet, mu, va);
}

extern "C" void kernel_launch(void* const* d_in, const int* in_sizes, int n_in,
                              void* d_out, int out_size, void* d_ws, size_t ws_size,
                              hipStream_t stream)
{
    const int*   text   = (const int*)d_in[0];
    const float* mel_t  = (const float*)d_in[1];
    const float* emb    = (const float*)d_in[2];
    const float* conv_w = (const float*)d_in[3];
    const float* conv_b = (const float*)d_in[4];
    const float* bn_g   = (const float*)d_in[5];
    const float* bn_b   = (const float*)d_in[6];
    const float* bn_m   = (const float*)d_in[7];
    const float* bn_v   = (const float*)d_in[8];
    const float* Wih_f  = (const float*)d_in[9];
    const float* Whh_f  = (const float*)d_in[10];
    const float* b_f    = (const float*)d_in[11];
    const float* Wih_b  = (const float*)d_in[12];
    const float* Whh_b  = (const float*)d_in[13];
    const float* b_b    = (const float*)d_in[14];
    const float* Wq     = (const float*)d_in[15];
    const float* bq     = (const float*)d_in[16];
    const float* Wk     = (const float*)d_in[17];
    const float* bk     = (const float*)d_in[18];
    const float* Wv     = (const float*)d_in[19];
    const float* bv     = (const float*)d_in[20];
    const float* Wo     = (const float*)d_in[21];
    const float* bo     = (const float*)d_in[22];
    const float* Wih1   = (const float*)d_in[23];
    const float* b1     = (const float*)d_in[24];
    const float* Wih2   = (const float*)d_in[25];
    const float* b2     = (const float*)d_in[26];
    const float* melW   = (const float*)d_in[27];
    const float* melb   = (const float*)d_in[28];
    const float* stopW  = (const float*)d_in[29];
    const float* stopb  = (const float*)d_in[30];
    float* out = (float*)d_out;
    (void)in_sizes; (void)n_in; (void)out_size; (void)ws_size;

    float* ws = (float*)d_ws;
    float* big  = ws;                       // 13107200 f: im2col | scores fp32 | h2
    float* pool = ws + 13107200;

    int*      flags  = (int*)(ws + 6000000);            // [2][2][256] (quiet window of big)
    _Float16* hstage = (_Float16*)(ws + 6000000 + 1024);// [2][16][256]

    // phase A/B (encoder)
    float*          gi_f   = pool + 0;
    float*          gi_b   = pool + 4194304;
    unsigned short* enc_bf = (unsigned short*)(pool + 8388608);
    float*          P0     = pool + 9437184;
    float*          P1     = pool + 11534336;
    unsigned short* xsT    = (unsigned short*)(pool + 13631488);
    // phase C (attention)
    unsigned short* kbf    = (unsigned short*)(pool + 0);          // 4096x512
    unsigned short* vT     = (unsigned short*)(pool + 1048576);    // 64x128x256
    unsigned short* qbf    = (unsigned short*)(pool + 2097152);    // 12928x512
    unsigned short* probs  = (unsigned short*)(pool + 9437184);    // 51328x256
    unsigned short* dinb   = (unsigned short*)(pool + 16008192);   // 12800x96
    unsigned short* ctxb   = (unsigned short*)(pool + 16622592);   // 12800x512
    // phase D (decoder)
    float*          gates  = pool + 0;                             // 3200x3072
    unsigned short* h1b    = (unsigned short*)(pool + 9830400);    // 12800x1024
    unsigned short* xcat   = (unsigned short*)(pool + 19899392);   // 12800x608
    // weights
    float*          WB     = pool + 23790592;
    unsigned short* cWc  = (unsigned short*)(WB + 0);
    unsigned short* cWif = (unsigned short*)(WB + 1966080);
    unsigned short* cWib = (unsigned short*)(WB + 2228224);
    unsigned short* cWk  = (unsigned short*)(WB + 2490368);
    unsigned short* cWv  = (unsigned short*)(WB + 2621440);
    unsigned short* cWq  = (unsigned short*)(WB + 2752512);
    unsigned short* cWo  = (unsigned short*)(WB + 2777088);
    unsigned short* cW1  = (unsigned short*)(WB + 2908160);
    unsigned short* cW2  = (unsigned short*)(WB + 3842048);

    auto ceil256 = [](int n) { return (n + 255) / 256; };

    hipMemsetAsync(flags, 0, 1024 * 4, stream);

    // ---- weight conversions ----
    cvt_bf<<<ceil256(1536 * 2560), 256, 0, stream>>>(conv_w, cWc, 1536, 2560, 2560);
    cvt_bf<<<ceil256(1024 * 512), 256, 0, stream>>>(Wih_f, cWif, 1024, 512, 512);
    cvt_bf<<<ceil256(1024 * 512), 256, 0, stream>>>(Wih_b, cWib, 1024, 512, 512);
    cvt_bf<<<ceil256(512 * 512), 256, 0, stream>>>(Wk, cWk, 512, 512, 512);
    cvt_bf<<<ceil256(512 * 512), 256, 0, stream>>>(Wv, cWv, 512, 512, 512);
    cvt_bf<<<ceil256(512 * 96), 256, 0, stream>>>(Wq, cWq, 512, 80, 96);
    cvt_bf<<<ceil256(512 * 512), 256, 0, stream>>>(Wo, cWo, 512, 512, 512);
    cvt_w1<<<ceil256(3072 * 608), 256, 0, stream>>>(Wih1, cW1);
    cvt_w2<<<ceil256(3072 * 1024), 256, 0, stream>>>(Wih2, cW2);

    // ---- encoder: embedding + 3 convs ----
    embed_k<<<ceil256(B_ * S_ * D_), 256, 0, stream>>>(text, emb, P0);
    float* cin = P0;
    float* cout = P1;
    for (int l = 0; l < 3; ++l) {
        im2col_bf<<<ceil256(B_ * S_ * 2560), 256, 0, stream>>>(cin, (unsigned short*)big);
        launch_mfma(stream, (unsigned short*)big, cWc + (size_t)l * 512 * 2560,
                    cout, nullptr, B_ * S_, 512, 2560, 512, 1,
                    conv_b + l * 512, bn_g + l * 512, bn_b + l * 512, bn_m + l * 512, bn_v + l * 512);
        float* tmp = cin; cin = cout; cout = tmp;
    }
    transp_bf<<<ceil256(B_ * S_ * D_), 256, 0, stream>>>(cin, xsT);

    // ---- encoder LSTM ----
    launch_mfma(stream, xsT, cWif, gi_f, b_f, S_ * B_, 1024, 512, 1024);
    launch_mfma(stream, xsT, cWib, gi_b, b_b, S_ * B_, 1024, 512, 1024);
    lstm_persist3<<<4, 1024, 0, stream>>>(gi_f, gi_b, Whh_f, Whh_b, enc_bf, hstage, flags);

    // ---- attention projections (bf16 outputs; v stored transposed) ----
    launch_mfma(stream, enc_bf, cWk, kbf, bk, B_ * S_, 512, 512, 512, 2);
    launch_mfma(stream, enc_bf, cWv, vT, bv, B_ * S_, 512, 512, 0, 3);
    decin_k2<<<ceil256(B_ * T_ * 96), 256, 0, stream>>>(mel_t, dinb, xcat);
    launch_mfma(stream, dinb, cWq, qbf, bq, B_ * T_, 512, 96, 512, 2);

    // ---- attention: MFMA scores -> softmax -> MFMA PV ----
    attn_qk<<<dim3(2, 7, 64), 256, 0, stream>>>(qbf, kbf, big);
    attn_sm<<<12800, 256, 0, stream>>>(big, probs);
    attn_pv<<<dim3(1, 7, 64), 256, 0, stream>>>(probs, vT, ctxb);

    // ---- Wo projection -> xcat[:, 0:512) bf16 ----
    launch_mfma(stream, ctxb, cWo, xcat, bo, B_ * T_, 512, 512, 608, 2);

    // ---- decoder cells (f-gate dropped; N=3072 = [i;g;o]) ----
    float* h2 = big;
    const int MC = 3200;
    for (int c0 = 0; c0 < B_ * T_; c0 += MC) {
        launch_mfma(stream, xcat + (size_t)c0 * 608, cW1, gates, nullptr, MC, 3072, 608, 3072);
        dec_cell1<<<ceil256(MC * H_), 256, 0, stream>>>(gates, b1, h1b + (size_t)c0 * H_, MC);
    }
    for (int c0 = 0; c0 < B_ * T_; c0 += MC) {
        launch_mfma(stream, h1b + (size_t)c0 * H_, cW2, gates, nullptr, MC, 3072, 1024, 3072);
        dec_cell2<<<ceil256(MC * H_), 256, 0, stream>>>(gates, b2, h2 + (size_t)c0 * H_, MC);
    }

    // ---- output heads ----
    {
        dim3 grid((80 + 63) / 64, (B_ * T_) / 64);
        gemm_tile<<<grid, 256, 0, stream>>>(h2, 1024, melW, melb, out, 80, B_ * T_, 80, 1024);
    }
    stop_head<<<(B_ * T_) / 4, 256, 0, stream>>>(h2, stopW, stopb, out + (size_t)B_ * T_ * M_);
}

// Round 6
// 1912.304 us; speedup vs baseline: 1.6022x; 1.6022x over previous
//
#include <hip/hip_runtime.h>
#include <hip/hip_bf16.h>
#include <math.h>

#define B_ 16
#define S_ 256
#define T_ 800
#define V_ 256
#define D_ 512
#define M_ 80
#define H_ 1024
#define NH_ 4
#define HD_ 128
#define EH_ 256

using bf16x8 = __attribute__((ext_vector_type(8))) short;
using f32x4  = __attribute__((ext_vector_type(4))) float;
typedef _Float16 half8 __attribute__((ext_vector_type(8)));

__device__ __forceinline__ float sigf(float x) { return 1.f / (1.f + __expf(-x)); }
__device__ __forceinline__ float tanhfast(float x) {
    float e = __expf(2.f * x);
    return 1.f - 2.f / (e + 1.f);
}

__device__ __forceinline__ unsigned short f2bf(float f) {
    unsigned int u = __float_as_uint(f);
    unsigned int r = (u + 0x7FFFu + ((u >> 16) & 1u)) >> 16;
    return (unsigned short)r;
}

__device__ __forceinline__ void gl_lds16(const unsigned short* g, unsigned short* l) {
    __builtin_amdgcn_global_load_lds((const __attribute__((address_space(1))) void*)g,
                                     (__attribute__((address_space(3))) void*)l, 16, 0, 0);
}

// ---------------- MFMA bf16 GEMM: C = A(M,K) @ B(N,K)^T --------------------
// epi: 0 fp32 out(+bias), 1 conv BN+ReLU fp32, 2 bf16 out(+bias), 3 v^T bf16 store
__global__ __launch_bounds__(256) void gemm_mfma(
    const unsigned short* __restrict__ A, const unsigned short* __restrict__ Bw,
    void* __restrict__ Cv, const float* __restrict__ bias,
    int M, int N, int K, int ldc, int epi,
    const float* __restrict__ cb, const float* __restrict__ gam,
    const float* __restrict__ bet, const float* __restrict__ mu,
    const float* __restrict__ va)
{
    __shared__ unsigned short As[4096];
    __shared__ unsigned short Bs[4096];
    const int tid = threadIdx.x, w = tid >> 6, lane = tid & 63;
    const int bm = blockIdx.y * 128, bn = blockIdx.x * 128;
    const int wr = w >> 1, wc = w & 1;

    f32x4 acc[4][4];
#pragma unroll
    for (int m = 0; m < 4; ++m)
#pragma unroll
        for (int n = 0; n < 4; ++n) acc[m][n] = (f32x4){0.f, 0.f, 0.f, 0.f};

    const int r0 = w * 16 + (lane >> 2);
    const int k8 = (lane & 3) * 8;
    const unsigned short* Ag = A + (size_t)(bm + r0) * K + k8;
    const unsigned short* Bg = Bw + (size_t)(bn + r0) * K + k8;
    unsigned short* Al = As + w * 512;
    unsigned short* Bl = Bs + w * 512;

    for (int k0 = 0; k0 < K; k0 += 32) {
        __syncthreads();
        gl_lds16(Ag + k0, Al);
        gl_lds16(Ag + (size_t)64 * K + k0, Al + 2048);
        gl_lds16(Bg + k0, Bl);
        gl_lds16(Bg + (size_t)64 * K + k0, Bl + 2048);
        __syncthreads();
        bf16x8 a[4], b[4];
#pragma unroll
        for (int m = 0; m < 4; ++m)
            a[m] = *(const bf16x8*)(As + (wr * 64 + m * 16 + (lane & 15)) * 32 + (lane >> 4) * 8);
#pragma unroll
        for (int n = 0; n < 4; ++n)
            b[n] = *(const bf16x8*)(Bs + (wc * 64 + n * 16 + (lane & 15)) * 32 + (lane >> 4) * 8);
#pragma unroll
        for (int m = 0; m < 4; ++m)
#pragma unroll
            for (int n = 0; n < 4; ++n)
                acc[m][n] = __builtin_amdgcn_mfma_f32_16x16x32_bf16(a[m], b[n], acc[m][n], 0, 0, 0);
    }

    const int cr = (lane >> 4) * 4, ccol = lane & 15;
#pragma unroll
    for (int m = 0; m < 4; ++m)
#pragma unroll
        for (int n = 0; n < 4; ++n) {
            const int col = bn + wc * 64 + n * 16 + ccol;
            const float bv = bias ? bias[col] : 0.f;
#pragma unroll
            for (int j = 0; j < 4; ++j) {
                const int row = bm + wr * 64 + m * 16 + cr + j;
                float v = acc[m][n][j] + bv;
                if (epi == 1) {
                    float x = v + cb[col];
                    v = fmaxf(0.f, gam[col] * (x - mu[col]) * rsqrtf(va[col] + 1e-5f) + bet[col]);
                }
                if (epi == 2) {
                    ((unsigned short*)Cv)[(size_t)row * ldc + col] = f2bf(v);
                } else if (epi == 3) {
                    const int bb2 = row >> 8, ss = row & 255, hh = col >> 7, dd = col & 127;
                    ((unsigned short*)Cv)[((size_t)(bb2 * 4 + hh) * 128 + dd) * 256 + ss] = f2bf(v);
                } else {
                    ((float*)Cv)[(size_t)row * ldc + col] = v;
                }
            }
        }
}

// ---------------- attention QK^T (per b,h): scores = q @ k^T * scale -------
__global__ __launch_bounds__(256) void attn_qk(
    const unsigned short* __restrict__ q, const unsigned short* __restrict__ k,
    float* __restrict__ scores)
{
    __shared__ unsigned short As[4096];
    __shared__ unsigned short Bs[4096];
    const int tid = threadIdx.x, w = tid >> 6, lane = tid & 63;
    const int bm = blockIdx.y * 128, bn = blockIdx.x * 128;
    const int z = blockIdx.z, b = z >> 2, h = z & 3;
    const int wr = w >> 1, wc = w & 1;

    const unsigned short* A  = q + ((size_t)b * T_) * 512 + h * 128;
    const unsigned short* Bw = k + ((size_t)b * S_) * 512 + h * 128;

    f32x4 acc[4][4];
#pragma unroll
    for (int m = 0; m < 4; ++m)
#pragma unroll
        for (int n = 0; n < 4; ++n) acc[m][n] = (f32x4){0.f, 0.f, 0.f, 0.f};

    const int r0 = w * 16 + (lane >> 2);
    const int k8 = (lane & 3) * 8;
    const unsigned short* Ag = A + (size_t)(bm + r0) * 512 + k8;
    const unsigned short* Bg = Bw + (size_t)(bn + r0) * 512 + k8;
    unsigned short* Al = As + w * 512;
    unsigned short* Bl = Bs + w * 512;

    for (int k0 = 0; k0 < 128; k0 += 32) {
        __syncthreads();
        gl_lds16(Ag + k0, Al);
        gl_lds16(Ag + (size_t)64 * 512 + k0, Al + 2048);
        gl_lds16(Bg + k0, Bl);
        gl_lds16(Bg + (size_t)64 * 512 + k0, Bl + 2048);
        __syncthreads();
        bf16x8 a[4], bfr[4];
#pragma unroll
        for (int m = 0; m < 4; ++m)
            a[m] = *(const bf16x8*)(As + (wr * 64 + m * 16 + (lane & 15)) * 32 + (lane >> 4) * 8);
#pragma unroll
        for (int n = 0; n < 4; ++n)
            bfr[n] = *(const bf16x8*)(Bs + (wc * 64 + n * 16 + (lane & 15)) * 32 + (lane >> 4) * 8);
#pragma unroll
        for (int m = 0; m < 4; ++m)
#pragma unroll
            for (int n = 0; n < 4; ++n)
                acc[m][n] = __builtin_amdgcn_mfma_f32_16x16x32_bf16(a[m], bfr[n], acc[m][n], 0, 0, 0);
    }

    const int cr = (lane >> 4) * 4, ccol = lane & 15;
#pragma unroll
    for (int m = 0; m < 4; ++m)
#pragma unroll
        for (int n = 0; n < 4; ++n) {
            const int col = bn + wc * 64 + n * 16 + ccol;
#pragma unroll
            for (int j = 0; j < 4; ++j) {
                const int row = bm + wr * 64 + m * 16 + cr + j;
                if (row < T_)
                    scores[((size_t)z * T_ + row) * 256 + col] = acc[m][n][j] * 0.08838834764831843f;
            }
        }
}

// ---------------- softmax over s (wave per row) ----------------------------
__global__ __launch_bounds__(256) void attn_sm(
    const float* __restrict__ scores, unsigned short* __restrict__ probs)
{
    const int row = blockIdx.x * 4 + (threadIdx.x >> 6);
    const int lane = threadIdx.x & 63;
    const float4 v = *(const float4*)(scores + (size_t)row * 256 + lane * 4);
    float m = fmaxf(fmaxf(v.x, v.y), fmaxf(v.z, v.w));
    for (int off = 32; off; off >>= 1) m = fmaxf(m, __shfl_xor(m, off));
    float ex = __expf(v.x - m), ey = __expf(v.y - m), ez = __expf(v.z - m), ew = __expf(v.w - m);
    float sum = ex + ey + ez + ew;
    for (int off = 32; off; off >>= 1) sum += __shfl_xor(sum, off);
    const float inv = 1.f / sum;
    ushort4 o;
    o.x = f2bf(ex * inv); o.y = f2bf(ey * inv); o.z = f2bf(ez * inv); o.w = f2bf(ew * inv);
    *(ushort4*)(probs + (size_t)row * 256 + lane * 4) = o;
}

// ---------------- attention PV (per b,h): ctx = probs @ vT^T ---------------
__global__ __launch_bounds__(256) void attn_pv(
    const unsigned short* __restrict__ probs, const unsigned short* __restrict__ vT,
    unsigned short* __restrict__ ctx)
{
    __shared__ unsigned short As[4096];
    __shared__ unsigned short Bs[4096];
    const int tid = threadIdx.x, w = tid >> 6, lane = tid & 63;
    const int bm = blockIdx.y * 128;
    const int z = blockIdx.z, b = z >> 2, h = z & 3;
    const int wr = w >> 1, wc = w & 1;

    const unsigned short* A  = probs + (size_t)z * T_ * 256;
    const unsigned short* Bw = vT + (size_t)z * 128 * 256;

    f32x4 acc[4][4];
#pragma unroll
    for (int m = 0; m < 4; ++m)
#pragma unroll
        for (int n = 0; n < 4; ++n) acc[m][n] = (f32x4){0.f, 0.f, 0.f, 0.f};

    const int r0 = w * 16 + (lane >> 2);
    const int k8 = (lane & 3) * 8;
    const unsigned short* Ag = A + (size_t)(bm + r0) * 256 + k8;
    const unsigned short* Bg = Bw + (size_t)r0 * 256 + k8;
    unsigned short* Al = As + w * 512;
    unsigned short* Bl = Bs + w * 512;

    for (int k0 = 0; k0 < 256; k0 += 32) {
        __syncthreads();
        gl_lds16(Ag + k0, Al);
        gl_lds16(Ag + (size_t)64 * 256 + k0, Al + 2048);
        gl_lds16(Bg + k0, Bl);
        gl_lds16(Bg + (size_t)64 * 256 + k0, Bl + 2048);
        __syncthreads();
        bf16x8 a[4], bfr[4];
#pragma unroll
        for (int m = 0; m < 4; ++m)
            a[m] = *(const bf16x8*)(As + (wr * 64 + m * 16 + (lane & 15)) * 32 + (lane >> 4) * 8);
#pragma unroll
        for (int n = 0; n < 4; ++n)
            bfr[n] = *(const bf16x8*)(Bs + (wc * 64 + n * 16 + (lane & 15)) * 32 + (lane >> 4) * 8);
#pragma unroll
        for (int m = 0; m < 4; ++m)
#pragma unroll
            for (int n = 0; n < 4; ++n)
                acc[m][n] = __builtin_amdgcn_mfma_f32_16x16x32_bf16(a[m], bfr[n], acc[m][n], 0, 0, 0);
    }

    const int cr = (lane >> 4) * 4, ccol = lane & 15;
#pragma unroll
    for (int m = 0; m < 4; ++m)
#pragma unroll
        for (int n = 0; n < 4; ++n) {
            const int col = wc * 64 + n * 16 + ccol;   // d in [0,128)
#pragma unroll
            for (int j = 0; j < 4; ++j) {
                const int row = bm + wr * 64 + m * 16 + cr + j;
                if (row < T_)
                    ctx[((size_t)b * T_ + row) * 512 + h * 128 + col] = f2bf(acc[m][n][j]);
            }
        }
}

// ---------------- fp32 tiled GEMM (mel head, N=80) --------------------------
__global__ __launch_bounds__(256) void gemm_tile(
    const float* __restrict__ A, int lda,
    const float* __restrict__ Bw,
    const float* __restrict__ bias,
    float* __restrict__ C, int ldc,
    int M, int N, int K)
{
    __shared__ float As[16][68];
    __shared__ float Bs[16][68];
    const int tid = threadIdx.x;
    const int bm = blockIdx.y * 64, bn = blockIdx.x * 64;
    const int tx = tid & 15, ty = tid >> 4;
    const int lr = tid >> 2, lk = (tid & 3) * 4;

    float acc[4][4] = {};

    const float* Aptr = A + (size_t)(bm + lr) * lda + lk;
    const bool bvalid = (bn + lr) < N;
    const float* Bptr = Bw + (size_t)(bvalid ? (bn + lr) : 0) * K + lk;

    for (int k0 = 0; k0 < K; k0 += 16) {
        float4 av = *(const float4*)(Aptr + k0);
        float4 bw = bvalid ? *(const float4*)(Bptr + k0) : make_float4(0.f, 0.f, 0.f, 0.f);
        As[lk + 0][lr] = av.x; As[lk + 1][lr] = av.y; As[lk + 2][lr] = av.z; As[lk + 3][lr] = av.w;
        Bs[lk + 0][lr] = bw.x; Bs[lk + 1][lr] = bw.y; Bs[lk + 2][lr] = bw.z; Bs[lk + 3][lr] = bw.w;
        __syncthreads();
#pragma unroll
        for (int k = 0; k < 16; ++k) {
            float4 a = *(const float4*)&As[k][ty * 4];
            float4 b = *(const float4*)&Bs[k][tx * 4];
            acc[0][0] += a.x * b.x; acc[0][1] += a.x * b.y; acc[0][2] += a.x * b.z; acc[0][3] += a.x * b.w;
            acc[1][0] += a.y * b.x; acc[1][1] += a.y * b.y; acc[1][2] += a.y * b.z; acc[1][3] += a.y * b.w;
            acc[2][0] += a.z * b.x; acc[2][1] += a.z * b.y; acc[2][2] += a.z * b.z; acc[2][3] += a.z * b.w;
            acc[3][0] += a.w * b.x; acc[3][1] += a.w * b.y; acc[3][2] += a.w * b.z; acc[3][3] += a.w * b.w;
        }
        __syncthreads();
    }

    const int row0 = bm + ty * 4, col0 = bn + tx * 4;
#pragma unroll
    for (int i = 0; i < 4; ++i)
#pragma unroll
        for (int j = 0; j < 4; ++j) {
            int cc = col0 + j;
            if (cc < N) {
                float v = acc[i][j];
                if (bias) v += bias[cc];
                C[(size_t)(row0 + i) * ldc + cc] = v;
            }
        }
}

// ---------------- elementwise / conversion kernels -------------------------
__global__ void embed_k(const int* __restrict__ txt, const float* __restrict__ emb,
                        float* __restrict__ xs)
{
    int idx = blockIdx.x * 256 + threadIdx.x;
    if (idx >= B_ * S_ * D_) return;
    int bs = idx >> 9, dd = idx & 511;
    xs[idx] = emb[(size_t)txt[bs] * D_ + dd];
}

__global__ void im2col_bf(const float* __restrict__ in, unsigned short* __restrict__ out)
{
    int idx = blockIdx.x * 256 + threadIdx.x;
    if (idx >= B_ * S_ * 2560) return;
    int r = idx / 2560, cc = idx % 2560;
    int din = cc / 5, kk = cc % 5;
    int b = r >> 8, s = r & 255;
    int sp = s + kk - 2;
    float v = (sp >= 0 && sp < S_) ? in[((size_t)b * S_ + sp) * D_ + din] : 0.f;
    out[idx] = f2bf(v);
}

__global__ void transp_bf(const float* __restrict__ in, unsigned short* __restrict__ out)
{
    int idx = blockIdx.x * 256 + threadIdx.x;
    if (idx >= B_ * S_ * D_) return;
    int d = idx & 511;
    int sb = idx >> 9;
    int s = sb >> 4, b = sb & 15;
    out[idx] = f2bf(in[((size_t)b * S_ + s) * D_ + d]);
}

// hist (f16, [dir][b][s][256]) -> enc (bf16, [b][s][512])
__global__ void hist2enc(const _Float16* __restrict__ hist, unsigned short* __restrict__ enc)
{
    int idx = blockIdx.x * 256 + threadIdx.x;
    if (idx >= B_ * S_ * D_) return;
    int d = idx & 511;
    int bs = idx >> 9;
    int b = bs >> 8, s = bs & 255;
    int dir = d >> 8, hid = d & 255;
    enc[idx] = f2bf((float)hist[(((size_t)(dir * 16 + b) * 256 + s) * 256) + hid]);
}

__global__ void cvt_bf(const float* __restrict__ in, unsigned short* __restrict__ out,
                       int rows, int Kin, int Kout)
{
    int idx = blockIdx.x * 256 + threadIdx.x;
    if (idx >= rows * Kout) return;
    int r = idx / Kout, k = idx - r * Kout;
    out[idx] = (k < Kin) ? f2bf(in[(size_t)r * Kin + k]) : 0;
}

__global__ void cvt_w1(const float* __restrict__ W, unsigned short* __restrict__ out)
{
    int idx = blockIdx.x * 256 + threadIdx.x;
    if (idx >= 3072 * 608) return;
    int n = idx / 608, k = idx - n * 608;
    int orig = (n < 1024) ? n : n + 1024;
    out[idx] = (k < 592) ? f2bf(W[(size_t)orig * 592 + k]) : 0;
}

__global__ void cvt_w2(const float* __restrict__ W, unsigned short* __restrict__ out)
{
    int idx = blockIdx.x * 256 + threadIdx.x;
    if (idx >= 3072 * 1024) return;
    int n = idx >> 10, k = idx & 1023;
    int orig = (n < 1024) ? n : n + 1024;
    out[idx] = f2bf(W[(size_t)orig * 1024 + k]);
}

__global__ void decin_k2(const float* __restrict__ mel, unsigned short* __restrict__ din,
                         unsigned short* __restrict__ xcat)
{
    int idx = blockIdx.x * 256 + threadIdx.x;
    if (idx >= B_ * T_ * 96) return;
    int r = idx / 96, j = idx - r * 96;
    int b = r / T_, t = r - b * T_;
    float v = (j < M_ && t > 0) ? mel[((size_t)b * T_ + t - 1) * M_ + j] : 0.f;
    unsigned short bv = f2bf(v);
    din[(size_t)r * 96 + j] = bv;
    xcat[(size_t)r * 608 + 512 + j] = bv;
}

__global__ void dec_cell1(const float* __restrict__ g, const float* __restrict__ b1,
                          unsigned short* __restrict__ h, int rows)
{
    int idx = blockIdx.x * 256 + threadIdx.x;
    if (idx >= rows * H_) return;
    int r = idx >> 10, j = idx & 1023;
    const float* gr = g + (size_t)r * 3072;
    float ig = sigf(gr[j] + b1[j]);
    float gg = tanhfast(gr[1024 + j] + b1[2048 + j]);
    float og = sigf(gr[2048 + j] + b1[3072 + j]);
    h[idx] = f2bf(og * tanhfast(ig * gg));
}

__global__ void dec_cell2(const float* __restrict__ g, const float* __restrict__ b2,
                          float* __restrict__ h, int rows)
{
    int idx = blockIdx.x * 256 + threadIdx.x;
    if (idx >= rows * H_) return;
    int r = idx >> 10, j = idx & 1023;
    const float* gr = g + (size_t)r * 3072;
    float ig = sigf(gr[j] + b2[j]);
    float gg = tanhfast(gr[1024 + j] + b2[2048 + j]);
    float og = sigf(gr[2048 + j] + b2[3072 + j]);
    h[idx] = og * tanhfast(ig * gg);
}

__global__ __launch_bounds__(256) void stop_head(
    const float* __restrict__ h2, const float* __restrict__ sw,
    const float* __restrict__ sb, float* __restrict__ out)
{
    int row = blockIdx.x * 4 + (threadIdx.x >> 6);
    int lane = threadIdx.x & 63;
    const float* hr = h2 + (size_t)row * H_;
    float acc = 0.f;
#pragma unroll
    for (int i = 0; i < H_; i += 64) acc += hr[i + lane] * sw[i + lane];
    for (int off = 32; off; off >>= 1) acc += __shfl_xor(acc, off);
    if (lane == 0) out[row] = acc + sb[0];
}

// ---------------- persistent LSTM: 2 blocks per direction ------------------
// All cross-block traffic via RELAXED agent-scope atomics (sc1, straight to
// LLC): no buffer_wbl2, no cache invalidates, no threadfence in the loop.
// Ordering: __syncthreads() drains vmcnt(0) (sc1 store-acks = at LLC) before
// the flag store; partner's post-barrier sc1 loads read LLC directly.
// h history written compactly (hist, plain stores); enc produced after by
// hist2enc (kernel boundary flushes L2).
__global__ __launch_bounds__(1024, 4) void lstm_persist4(
    const float* __restrict__ gi_f, const float* __restrict__ gi_b,
    const float* __restrict__ Wf, const float* __restrict__ Wb,
    _Float16* __restrict__ hist,          // [2][16][256][256] f16
    unsigned int* __restrict__ hstage,    // [2][16][128] uints (2 f16 each)
    int* __restrict__ flags)              // [2][2][256]
{
    const int blk = blockIdx.x;
    const int dir = blk >> 1, half = blk & 1;
    const float* gi = dir ? gi_b : gi_f;
    const float* W  = dir ? Wb : Wf;
    const int tid = threadIdx.x, wv = tid >> 6, lane = tid & 63;
    const int l15 = lane & 15, q = lane >> 4;

    __shared__ _Float16 h_lds[16][264];   // [batch][hid 0..255], pad 8
    __shared__ float exch[512][17];       // [gate*128+hid_local][batch], pad 1

    // --- preload W fragments: wave wv owns tiles wv and wv+16 ---
    half8 w0[8], w1[8];
    {
        const int gt0 = wv >> 3, hb0 = wv & 7;
        const int gt1 = (wv + 16) >> 3;
        const float* wr0 = W + (size_t)(gt0 * 256 + half * 128 + hb0 * 16 + l15) * 256;
        const float* wr1 = W + (size_t)(gt1 * 256 + half * 128 + hb0 * 16 + l15) * 256;
#pragma unroll
        for (int ks = 0; ks < 8; ++ks) {
            half8 a, b;
#pragma unroll
            for (int j = 0; j < 8; ++j) {
                a[j] = (_Float16)wr0[ks * 32 + q * 8 + j];
                b[j] = (_Float16)wr1[ks * 32 + q * 8 + j];
            }
            w0[ks] = a; w1[ks] = b;
        }
    }
    for (int i = tid; i < 16 * 264; i += 1024) ((_Float16*)h_lds)[i] = (_Float16)0.f;

    const int hid = tid & 127;
    const int ba  = tid >> 7;       // 0..7
    const int bb  = ba + 8;
    const int gh  = half * 128 + hid;
    float c0 = 0.f, c1 = 0.f;

    const int exr0 = (wv >> 3) * 128 + (wv & 7) * 16 + l15;
    const int exr1 = ((wv + 16) >> 3) * 128 + (wv & 7) * 16 + l15;

    // repack/exchange mapping (uint = 2 adjacent f16)
    const int rb = tid >> 6;                 // batch 0..15
    const int hp = tid & 63;                 // hid-pair 0..63
    const int own_col = half * 128 + hp * 2;
    const int own_u   = (dir * 16 + rb) * 128 + half * 64 + hp;
    const int par_col = (half ^ 1) * 128 + hp * 2;
    const int par_u   = (dir * 16 + rb) * 128 + (half ^ 1) * 64 + hp;

    int* myflag = flags + (dir * 2 + half) * 256;
    int* pflag  = flags + (dir * 2 + (half ^ 1)) * 256;

    // gi prefetch for step 0
    float gp0[4], gp1[4];
    {
        const int s0 = dir ? 255 : 0;
        const float* g0 = gi + ((size_t)s0 * 16 + ba) * 1024 + gh;
        const float* g1 = gi + ((size_t)s0 * 16 + bb) * 1024 + gh;
#pragma unroll
        for (int g2 = 0; g2 < 4; ++g2) { gp0[g2] = g0[g2 * 256]; gp1[g2] = g1[g2 * 256]; }
    }
    __syncthreads();

    for (int step = 0; step < 256; ++step) {
        const int s = dir ? (255 - step) : step;

        f32x4 acc0 = (f32x4){0.f, 0.f, 0.f, 0.f};
        f32x4 acc1 = (f32x4){0.f, 0.f, 0.f, 0.f};
#pragma unroll
        for (int ks = 0; ks < 8; ++ks) {
            half8 a = *(const half8*)&h_lds[l15][ks * 32 + q * 8];
            acc0 = __builtin_amdgcn_mfma_f32_16x16x32_f16(a, w0[ks], acc0, 0, 0, 0);
            acc1 = __builtin_amdgcn_mfma_f32_16x16x32_f16(a, w1[ks], acc1, 0, 0, 0);
        }
        *(f32x4*)&exch[exr0][q * 4] = acc0;
        *(f32x4*)&exch[exr1][q * 4] = acc1;
        __syncthreads();

        // ---- c/h update: 2 (hid,batch) pairs per thread ----
        float h0, h1;
        {
            float xi = exch[hid][ba] + gp0[0];
            float xf = exch[128 + hid][ba] + gp0[1];
            float xg = exch[256 + hid][ba] + gp0[2];
            float xo = exch[384 + hid][ba] + gp0[3];
            float ig = sigf(xi), fg = sigf(xf), gg = tanhfast(xg), og = sigf(xo);
            c0 = fg * c0 + ig * gg; h0 = og * tanhfast(c0);
            xi = exch[hid][bb] + gp1[0];
            xf = exch[128 + hid][bb] + gp1[1];
            xg = exch[256 + hid][bb] + gp1[2];
            xo = exch[384 + hid][bb] + gp1[3];
            ig = sigf(xi); fg = sigf(xf); gg = tanhfast(xg); og = sigf(xo);
            c1 = fg * c1 + ig * gg; h1 = og * tanhfast(c1);
        }
        h_lds[ba][gh] = (_Float16)h0;
        h_lds[bb][gh] = (_Float16)h1;
        hist[(((size_t)(dir * 16 + ba) * 256 + s) * 256) + gh] = (_Float16)h0;
        hist[(((size_t)(dir * 16 + bb) * 256 + s) * 256) + gh] = (_Float16)h1;
        __syncthreads();   // h_lds own-half complete -> repack

        // ---- repack own half: one uint per thread, straight to LLC ----
        {
            unsigned int v = *(const unsigned int*)&h_lds[rb][own_col];
            __hip_atomic_store(&hstage[own_u], v, __ATOMIC_RELAXED, __HIP_MEMORY_SCOPE_AGENT);
        }
        __syncthreads();   // vmcnt(0) drain: sc1 stores acked at LLC

        if (tid == 0)
            __hip_atomic_store(&myflag[step], 1, __ATOMIC_RELAXED, __HIP_MEMORY_SCOPE_AGENT);

        // ---- next-step gi prefetch (overlaps partner wait) ----
        if (step < 255) {
            const int s2 = dir ? (254 - step) : (step + 1);
            const float* g0 = gi + ((size_t)s2 * 16 + ba) * 1024 + gh;
            const float* g1 = gi + ((size_t)s2 * 16 + bb) * 1024 + gh;
#pragma unroll
            for (int g2 = 0; g2 < 4; ++g2) { gp0[g2] = g0[g2 * 256]; gp1[g2] = g1[g2 * 256]; }
        }

        if (tid == 0)
            while (__hip_atomic_load(&pflag[step], __ATOMIC_RELAXED, __HIP_MEMORY_SCOPE_AGENT) == 0)
                __builtin_amdgcn_s_sleep(1);
        __syncthreads();

        // ---- read partner half from LLC into LDS ----
        {
            unsigned int v = __hip_atomic_load(&hstage[par_u], __ATOMIC_RELAXED, __HIP_MEMORY_SCOPE_AGENT);
            *(unsigned int*)&h_lds[rb][par_col] = v;
        }
        __syncthreads();
    }
}

// ---------------- host orchestration --------------------------------------
static inline void launch_mfma(hipStream_t st, const unsigned short* A, const unsigned short* B,
                               void* C, const float* bias, int M, int N, int K, int ldc, int epi = 0,
                               const float* cb = nullptr, const float* gam = nullptr,
                               const float* bet = nullptr, const float* mu = nullptr,
                               const float* va = nullptr)
{
    dim3 grid(N / 128, M / 128);
    gemm_mfma<<<grid, 256, 0, st>>>(A, B, C, bias, M, N, K, ldc, epi, cb, gam, bet, mu, va);
}

extern "C" void kernel_launch(void* const* d_in, const int* in_sizes, int n_in,
                              void* d_out, int out_size, void* d_ws, size_t ws_size,
                              hipStream_t stream)
{
    const int*   text   = (const int*)d_in[0];
    const float* mel_t  = (const float*)d_in[1];
    const float* emb    = (const float*)d_in[2];
    const float* conv_w = (const float*)d_in[3];
    const float* conv_b = (const float*)d_in[4];
    const float* bn_g   = (const float*)d_in[5];
    const float* bn_b   = (const float*)d_in[6];
    const float* bn_m   = (const float*)d_in[7];
    const float* bn_v   = (const float*)d_in[8];
    const float* Wih_f  = (const float*)d_in[9];
    const float* Whh_f  = (const float*)d_in[10];
    const float* b_f    = (const float*)d_in[11];
    const float* Wih_b  = (const float*)d_in[12];
    const float* Whh_b  = (const float*)d_in[13];
    const float* b_b    = (const float*)d_in[14];
    const float* Wq     = (const float*)d_in[15];
    const float* bq     = (const float*)d_in[16];
    const float* Wk     = (const float*)d_in[17];
    const float* bk     = (const float*)d_in[18];
    const float* Wv     = (const float*)d_in[19];
    const float* bv     = (const float*)d_in[20];
    const float* Wo     = (const float*)d_in[21];
    const float* bo     = (const float*)d_in[22];
    const float* Wih1   = (const float*)d_in[23];
    const float* b1     = (const float*)d_in[24];
    const float* Wih2   = (const float*)d_in[25];
    const float* b2     = (const float*)d_in[26];
    const float* melW   = (const float*)d_in[27];
    const float* melb   = (const float*)d_in[28];
    const float* stopW  = (const float*)d_in[29];
    const float* stopb  = (const float*)d_in[30];
    float* out = (float*)d_out;
    (void)in_sizes; (void)n_in; (void)out_size; (void)ws_size;

    float* ws = (float*)d_ws;
    float* big  = ws;                       // 13107200 f: im2col | scores fp32 | h2
    float* pool = ws + 13107200;

    int*          flags  = (int*)(ws + 6000000);              // [2][2][256] (quiet window)
    unsigned int* hstage = (unsigned int*)(ws + 6000000 + 1024); // [2][16][128] uints

    // phase A/B (encoder)
    float*          gi_f   = pool + 0;
    float*          gi_b   = pool + 4194304;
    unsigned short* enc_bf = (unsigned short*)(pool + 8388608);
    float*          P0     = pool + 9437184;
    float*          P1     = pool + 11534336;
    unsigned short* xsT    = (unsigned short*)(pool + 13631488);
    _Float16*       hist   = (_Float16*)(pool + 14155776);     // 4MB f16 ..16252928
    // phase C (attention)
    unsigned short* kbf    = (unsigned short*)(pool + 0);          // 4096x512
    unsigned short* vT     = (unsigned short*)(pool + 1048576);    // 64x128x256
    unsigned short* qbf    = (unsigned short*)(pool + 2097152);    // 12928x512
    unsigned short* probs  = (unsigned short*)(pool + 9437184);    // 51328x256
    unsigned short* dinb   = (unsigned short*)(pool + 16008192);   // 12800x96 (after hist dead)
    unsigned short* ctxb   = (unsigned short*)(pool + 16622592);   // 12800x512
    // phase D (decoder)
    float*          gates  = pool + 0;                             // 3200x3072
    unsigned short* h1b    = (unsigned short*)(pool + 9830400);    // 12800x1024
    unsigned short* xcat   = (unsigned short*)(pool + 19899392);   // 12800x608
    // weights
    float*          WB     = pool + 23790592;
    unsigned short* cWc  = (unsigned short*)(WB + 0);
    unsigned short* cWif = (unsigned short*)(WB + 1966080);
    unsigned short* cWib = (unsigned short*)(WB + 2228224);
    unsigned short* cWk  = (unsigned short*)(WB + 2490368);
    unsigned short* cWv  = (unsigned short*)(WB + 2621440);
    unsigned short* cWq  = (unsigned short*)(WB + 2752512);
    unsigned short* cWo  = (unsigned short*)(WB + 2777088);
    unsigned short* cW1  = (unsigned short*)(WB + 2908160);
    unsigned short* cW2  = (unsigned short*)(WB + 3842048);

    auto ceil256 = [](int n) { return (n + 255) / 256; };

    hipMemsetAsync(flags, 0, 1024 * 4, stream);

    // ---- weight conversions ----
    cvt_bf<<<ceil256(1536 * 2560), 256, 0, stream>>>(conv_w, cWc, 1536, 2560, 2560);
    cvt_bf<<<ceil256(1024 * 512), 256, 0, stream>>>(Wih_f, cWif, 1024, 512, 512);
    cvt_bf<<<ceil256(1024 * 512), 256, 0, stream>>>(Wih_b, cWib, 1024, 512, 512);
    cvt_bf<<<ceil256(512 * 512), 256, 0, stream>>>(Wk, cWk, 512, 512, 512);
    cvt_bf<<<ceil256(512 * 512), 256, 0, stream>>>(Wv, cWv, 512, 512, 512);
    cvt_bf<<<ceil256(512 * 96), 256, 0, stream>>>(Wq, cWq, 512, 80, 96);
    cvt_bf<<<ceil256(512 * 512), 256, 0, stream>>>(Wo, cWo, 512, 512, 512);
    cvt_w1<<<ceil256(3072 * 608), 256, 0, stream>>>(Wih1, cW1);
    cvt_w2<<<ceil256(3072 * 1024), 256, 0, stream>>>(Wih2, cW2);

    // ---- encoder: embedding + 3 convs ----
    embed_k<<<ceil256(B_ * S_ * D_), 256, 0, stream>>>(text, emb, P0);
    float* cin = P0;
    float* cout = P1;
    for (int l = 0; l < 3; ++l) {
        im2col_bf<<<ceil256(B_ * S_ * 2560), 256, 0, stream>>>(cin, (unsigned short*)big);
        launch_mfma(stream, (unsigned short*)big, cWc + (size_t)l * 512 * 2560,
                    cout, nullptr, B_ * S_, 512, 2560, 512, 1,
                    conv_b + l * 512, bn_g + l * 512, bn_b + l * 512, bn_m + l * 512, bn_v + l * 512);
        float* tmp = cin; cin = cout; cout = tmp;
    }
    transp_bf<<<ceil256(B_ * S_ * D_), 256, 0, stream>>>(cin, xsT);

    // ---- encoder LSTM ----
    launch_mfma(stream, xsT, cWif, gi_f, b_f, S_ * B_, 1024, 512, 1024);
    launch_mfma(stream, xsT, cWib, gi_b, b_b, S_ * B_, 1024, 512, 1024);
    lstm_persist4<<<4, 1024, 0, stream>>>(gi_f, gi_b, Whh_f, Whh_b, hist, hstage, flags);
    hist2enc<<<ceil256(B_ * S_ * D_), 256, 0, stream>>>(hist, enc_bf);

    // ---- attention projections (bf16 outputs; v stored transposed) ----
    launch_mfma(stream, enc_bf, cWk, kbf, bk, B_ * S_, 512, 512, 512, 2);
    launch_mfma(stream, enc_bf, cWv, vT, bv, B_ * S_, 512, 512, 0, 3);
    decin_k2<<<ceil256(B_ * T_ * 96), 256, 0, stream>>>(mel_t, dinb, xcat);
    launch_mfma(stream, dinb, cWq, qbf, bq, B_ * T_, 512, 96, 512, 2);

    // ---- attention: MFMA scores -> softmax -> MFMA PV ----
    attn_qk<<<dim3(2, 7, 64), 256, 0, stream>>>(qbf, kbf, big);
    attn_sm<<<12800, 256, 0, stream>>>(big, probs);
    attn_pv<<<dim3(1, 7, 64), 256, 0, stream>>>(probs, vT, ctxb);

    // ---- Wo projection -> xcat[:, 0:512) bf16 ----
    launch_mfma(stream, ctxb, cWo, xcat, bo, B_ * T_, 512, 512, 608, 2);

    // ---- decoder cells (f-gate dropped; N=3072 = [i;g;o]) ----
    float* h2 = big;
    const int MC = 3200;
    for (int c0 = 0; c0 < B_ * T_; c0 += MC) {
        launch_mfma(stream, xcat + (size_t)c0 * 608, cW1, gates, nullptr, MC, 3072, 608, 3072);
        dec_cell1<<<ceil256(MC * H_), 256, 0, stream>>>(gates, b1, h1b + (size_t)c0 * H_, MC);
    }
    for (int c0 = 0; c0 < B_ * T_; c0 += MC) {
        launch_mfma(stream, h1b + (size_t)c0 * H_, cW2, gates, nullptr, MC, 3072, 1024, 3072);
        dec_cell2<<<ceil256(MC * H_), 256, 0, stream>>>(gates, b2, h2 + (size_t)c0 * H_, MC);
    }

    // ---- output heads ----
    {
        dim3 grid((80 + 63) / 64, (B_ * T_) / 64);
        gemm_tile<<<grid, 256, 0, stream>>>(h2, 1024, melW, melb, out, 80, B_ * T_, 80, 1024);
    }
    stop_head<<<(B_ * T_) / 4, 256, 0, stream>>>(h2, stopW, stopb, out + (size_t)B_ * T_ * M_);
}

// Round 7
// 1747.479 us; speedup vs baseline: 1.7533x; 1.0943x over previous
//
#include <hip/hip_runtime.h>
#include <hip/hip_bf16.h>
#include <math.h>

#define B_ 16
#define S_ 256
#define T_ 800
#define V_ 256
#define D_ 512
#define M_ 80
#define H_ 1024
#define NH_ 4
#define HD_ 128
#define EH_ 256

using bf16x8 = __attribute__((ext_vector_type(8))) short;
using f32x4  = __attribute__((ext_vector_type(4))) float;
typedef _Float16 half8 __attribute__((ext_vector_type(8)));

__device__ __forceinline__ float sigf(float x) { return 1.f / (1.f + __expf(-x)); }
__device__ __forceinline__ float tanhfast(float x) {
    float e = __expf(2.f * x);
    return 1.f - 2.f / (e + 1.f);
}

__device__ __forceinline__ unsigned short f2bf(float f) {
    unsigned int u = __float_as_uint(f);
    unsigned int r = (u + 0x7FFFu + ((u >> 16) & 1u)) >> 16;
    return (unsigned short)r;
}
__device__ __forceinline__ float bf2f(unsigned short u) {
    return __uint_as_float(((unsigned int)u) << 16);
}
__device__ __forceinline__ unsigned short h2u(_Float16 x) {
    union { _Float16 f; unsigned short u; } c; c.f = x; return c.u;
}

__device__ __forceinline__ void gl_lds16(const unsigned short* g, unsigned short* l) {
    __builtin_amdgcn_global_load_lds((const __attribute__((address_space(1))) void*)g,
                                     (__attribute__((address_space(3))) void*)l, 16, 0, 0);
}

// ---------------- MFMA bf16 GEMM: C = A(M,K) @ B(N,K)^T --------------------
// epi: 0 fp32(+bias), 1 conv BN+ReLU fp32, 2 bf16(+bias), 3 v^T bf16, 4 fp32 col<80
__global__ __launch_bounds__(256) void gemm_mfma(
    const unsigned short* __restrict__ A, const unsigned short* __restrict__ Bw,
    void* __restrict__ Cv, const float* __restrict__ bias,
    int M, int N, int K, int ldc, int epi,
    const float* __restrict__ cb, const float* __restrict__ gam,
    const float* __restrict__ bet, const float* __restrict__ mu,
    const float* __restrict__ va)
{
    __shared__ unsigned short As[4096];
    __shared__ unsigned short Bs[4096];
    const int tid = threadIdx.x, w = tid >> 6, lane = tid & 63;
    const int bm = blockIdx.y * 128, bn = blockIdx.x * 128;
    const int wr = w >> 1, wc = w & 1;

    f32x4 acc[4][4];
#pragma unroll
    for (int m = 0; m < 4; ++m)
#pragma unroll
        for (int n = 0; n < 4; ++n) acc[m][n] = (f32x4){0.f, 0.f, 0.f, 0.f};

    const int r0 = w * 16 + (lane >> 2);
    const int k8 = (lane & 3) * 8;
    const unsigned short* Ag = A + (size_t)(bm + r0) * K + k8;
    const unsigned short* Bg = Bw + (size_t)(bn + r0) * K + k8;
    unsigned short* Al = As + w * 512;
    unsigned short* Bl = Bs + w * 512;

    for (int k0 = 0; k0 < K; k0 += 32) {
        __syncthreads();
        gl_lds16(Ag + k0, Al);
        gl_lds16(Ag + (size_t)64 * K + k0, Al + 2048);
        gl_lds16(Bg + k0, Bl);
        gl_lds16(Bg + (size_t)64 * K + k0, Bl + 2048);
        __syncthreads();
        bf16x8 a[4], b[4];
#pragma unroll
        for (int m = 0; m < 4; ++m)
            a[m] = *(const bf16x8*)(As + (wr * 64 + m * 16 + (lane & 15)) * 32 + (lane >> 4) * 8);
#pragma unroll
        for (int n = 0; n < 4; ++n)
            b[n] = *(const bf16x8*)(Bs + (wc * 64 + n * 16 + (lane & 15)) * 32 + (lane >> 4) * 8);
#pragma unroll
        for (int m = 0; m < 4; ++m)
#pragma unroll
            for (int n = 0; n < 4; ++n)
                acc[m][n] = __builtin_amdgcn_mfma_f32_16x16x32_bf16(a[m], b[n], acc[m][n], 0, 0, 0);
    }

    const int cr = (lane >> 4) * 4, ccol = lane & 15;
#pragma unroll
    for (int m = 0; m < 4; ++m)
#pragma unroll
        for (int n = 0; n < 4; ++n) {
            const int col = bn + wc * 64 + n * 16 + ccol;
            const float bv = (bias && !(epi == 4 && col >= 80)) ? bias[col] : 0.f;
#pragma unroll
            for (int j = 0; j < 4; ++j) {
                const int row = bm + wr * 64 + m * 16 + cr + j;
                float v = acc[m][n][j] + bv;
                if (epi == 1) {
                    float x = v + cb[col];
                    v = fmaxf(0.f, gam[col] * (x - mu[col]) * rsqrtf(va[col] + 1e-5f) + bet[col]);
                }
                if (epi == 2) {
                    ((unsigned short*)Cv)[(size_t)row * ldc + col] = f2bf(v);
                } else if (epi == 3) {
                    const int bb2 = row >> 8, ss = row & 255, hh = col >> 7, dd = col & 127;
                    ((unsigned short*)Cv)[((size_t)(bb2 * 4 + hh) * 128 + dd) * 256 + ss] = f2bf(v);
                } else if (epi == 4) {
                    if (col < 80) ((float*)Cv)[(size_t)row * ldc + col] = v;
                } else {
                    ((float*)Cv)[(size_t)row * ldc + col] = v;
                }
            }
        }
}

// ---------------- attention QK^T ------------------------------------------
__global__ __launch_bounds__(256) void attn_qk(
    const unsigned short* __restrict__ q, const unsigned short* __restrict__ k,
    float* __restrict__ scores)
{
    __shared__ unsigned short As[4096];
    __shared__ unsigned short Bs[4096];
    const int tid = threadIdx.x, w = tid >> 6, lane = tid & 63;
    const int bm = blockIdx.y * 128, bn = blockIdx.x * 128;
    const int z = blockIdx.z, b = z >> 2, h = z & 3;
    const int wr = w >> 1, wc = w & 1;

    const unsigned short* A  = q + ((size_t)b * T_) * 512 + h * 128;
    const unsigned short* Bw = k + ((size_t)b * S_) * 512 + h * 128;

    f32x4 acc[4][4];
#pragma unroll
    for (int m = 0; m < 4; ++m)
#pragma unroll
        for (int n = 0; n < 4; ++n) acc[m][n] = (f32x4){0.f, 0.f, 0.f, 0.f};

    const int r0 = w * 16 + (lane >> 2);
    const int k8 = (lane & 3) * 8;
    const unsigned short* Ag = A + (size_t)(bm + r0) * 512 + k8;
    const unsigned short* Bg = Bw + (size_t)(bn + r0) * 512 + k8;
    unsigned short* Al = As + w * 512;
    unsigned short* Bl = Bs + w * 512;

    for (int k0 = 0; k0 < 128; k0 += 32) {
        __syncthreads();
        gl_lds16(Ag + k0, Al);
        gl_lds16(Ag + (size_t)64 * 512 + k0, Al + 2048);
        gl_lds16(Bg + k0, Bl);
        gl_lds16(Bg + (size_t)64 * 512 + k0, Bl + 2048);
        __syncthreads();
        bf16x8 a[4], bfr[4];
#pragma unroll
        for (int m = 0; m < 4; ++m)
            a[m] = *(const bf16x8*)(As + (wr * 64 + m * 16 + (lane & 15)) * 32 + (lane >> 4) * 8);
#pragma unroll
        for (int n = 0; n < 4; ++n)
            bfr[n] = *(const bf16x8*)(Bs + (wc * 64 + n * 16 + (lane & 15)) * 32 + (lane >> 4) * 8);
#pragma unroll
        for (int m = 0; m < 4; ++m)
#pragma unroll
            for (int n = 0; n < 4; ++n)
                acc[m][n] = __builtin_amdgcn_mfma_f32_16x16x32_bf16(a[m], bfr[n], acc[m][n], 0, 0, 0);
    }

    const int cr = (lane >> 4) * 4, ccol = lane & 15;
#pragma unroll
    for (int m = 0; m < 4; ++m)
#pragma unroll
        for (int n = 0; n < 4; ++n) {
            const int col = bn + wc * 64 + n * 16 + ccol;
#pragma unroll
            for (int j = 0; j < 4; ++j) {
                const int row = bm + wr * 64 + m * 16 + cr + j;
                if (row < T_)
                    scores[((size_t)z * T_ + row) * 256 + col] = acc[m][n][j] * 0.08838834764831843f;
            }
        }
}

// ---------------- softmax over s (wave per row) ----------------------------
__global__ __launch_bounds__(256) void attn_sm(
    const float* __restrict__ scores, unsigned short* __restrict__ probs)
{
    const int row = blockIdx.x * 4 + (threadIdx.x >> 6);
    const int lane = threadIdx.x & 63;
    const float4 v = *(const float4*)(scores + (size_t)row * 256 + lane * 4);
    float m = fmaxf(fmaxf(v.x, v.y), fmaxf(v.z, v.w));
    for (int off = 32; off; off >>= 1) m = fmaxf(m, __shfl_xor(m, off));
    float ex = __expf(v.x - m), ey = __expf(v.y - m), ez = __expf(v.z - m), ew = __expf(v.w - m);
    float sum = ex + ey + ez + ew;
    for (int off = 32; off; off >>= 1) sum += __shfl_xor(sum, off);
    const float inv = 1.f / sum;
    ushort4 o;
    o.x = f2bf(ex * inv); o.y = f2bf(ey * inv); o.z = f2bf(ez * inv); o.w = f2bf(ew * inv);
    *(ushort4*)(probs + (size_t)row * 256 + lane * 4) = o;
}

// ---------------- attention PV --------------------------------------------
__global__ __launch_bounds__(256) void attn_pv(
    const unsigned short* __restrict__ probs, const unsigned short* __restrict__ vT,
    unsigned short* __restrict__ ctx)
{
    __shared__ unsigned short As[4096];
    __shared__ unsigned short Bs[4096];
    const int tid = threadIdx.x, w = tid >> 6, lane = tid & 63;
    const int bm = blockIdx.y * 128;
    const int z = blockIdx.z, b = z >> 2, h = z & 3;
    const int wr = w >> 1, wc = w & 1;

    const unsigned short* A  = probs + (size_t)z * T_ * 256;
    const unsigned short* Bw = vT + (size_t)z * 128 * 256;

    f32x4 acc[4][4];
#pragma unroll
    for (int m = 0; m < 4; ++m)
#pragma unroll
        for (int n = 0; n < 4; ++n) acc[m][n] = (f32x4){0.f, 0.f, 0.f, 0.f};

    const int r0 = w * 16 + (lane >> 2);
    const int k8 = (lane & 3) * 8;
    const unsigned short* Ag = A + (size_t)(bm + r0) * 256 + k8;
    const unsigned short* Bg = Bw + (size_t)r0 * 256 + k8;
    unsigned short* Al = As + w * 512;
    unsigned short* Bl = Bs + w * 512;

    for (int k0 = 0; k0 < 256; k0 += 32) {
        __syncthreads();
        gl_lds16(Ag + k0, Al);
        gl_lds16(Ag + (size_t)64 * 256 + k0, Al + 2048);
        gl_lds16(Bg + k0, Bl);
        gl_lds16(Bg + (size_t)64 * 256 + k0, Bl + 2048);
        __syncthreads();
        bf16x8 a[4], bfr[4];
#pragma unroll
        for (int m = 0; m < 4; ++m)
            a[m] = *(const bf16x8*)(As + (wr * 64 + m * 16 + (lane & 15)) * 32 + (lane >> 4) * 8);
#pragma unroll
        for (int n = 0; n < 4; ++n)
            bfr[n] = *(const bf16x8*)(Bs + (wc * 64 + n * 16 + (lane & 15)) * 32 + (lane >> 4) * 8);
#pragma unroll
        for (int m = 0; m < 4; ++m)
#pragma unroll
            for (int n = 0; n < 4; ++n)
                acc[m][n] = __builtin_amdgcn_mfma_f32_16x16x32_bf16(a[m], bfr[n], acc[m][n], 0, 0, 0);
    }

    const int cr = (lane >> 4) * 4, ccol = lane & 15;
#pragma unroll
    for (int m = 0; m < 4; ++m)
#pragma unroll
        for (int n = 0; n < 4; ++n) {
            const int col = wc * 64 + n * 16 + ccol;
#pragma unroll
            for (int j = 0; j < 4; ++j) {
                const int row = bm + wr * 64 + m * 16 + cr + j;
                if (row < T_)
                    ctx[((size_t)b * T_ + row) * 512 + h * 128 + col] = f2bf(acc[m][n][j]);
            }
        }
}

// ---------------- elementwise / conversion kernels -------------------------
__global__ void embed_k(const int* __restrict__ txt, const float* __restrict__ emb,
                        float* __restrict__ xs)
{
    int idx = blockIdx.x * 256 + threadIdx.x;
    if (idx >= B_ * S_ * D_) return;
    int bs = idx >> 9, dd = idx & 511;
    xs[idx] = emb[(size_t)txt[bs] * D_ + dd];
}

__global__ void im2col_bf(const float* __restrict__ in, unsigned short* __restrict__ out)
{
    int idx = blockIdx.x * 256 + threadIdx.x;
    if (idx >= B_ * S_ * 2560) return;
    int r = idx / 2560, cc = idx % 2560;
    int din = cc / 5, kk = cc % 5;
    int b = r >> 8, s = r & 255;
    int sp = s + kk - 2;
    float v = (sp >= 0 && sp < S_) ? in[((size_t)b * S_ + sp) * D_ + din] : 0.f;
    out[idx] = f2bf(v);
}

__global__ void transp_bf(const float* __restrict__ in, unsigned short* __restrict__ out)
{
    int idx = blockIdx.x * 256 + threadIdx.x;
    if (idx >= B_ * S_ * D_) return;
    int d = idx & 511;
    int sb = idx >> 9;
    int s = sb >> 4, b = sb & 15;
    out[idx] = f2bf(in[((size_t)b * S_ + s) * D_ + d]);
}

// hist (f16, [dir][b][s][256]) -> enc (bf16, [b][s][512])
__global__ void hist2enc(const _Float16* __restrict__ hist, unsigned short* __restrict__ enc)
{
    int idx = blockIdx.x * 256 + threadIdx.x;
    if (idx >= B_ * S_ * D_) return;
    int d = idx & 511;
    int bs = idx >> 9;
    int b = bs >> 8, s = bs & 255;
    int dir = d >> 8, hid = d & 255;
    enc[idx] = f2bf((float)hist[(((size_t)(dir * 16 + b) * 256 + s) * 256) + hid]);
}

__global__ void cvt_bf(const float* __restrict__ in, unsigned short* __restrict__ out,
                       int rows, int Kin, int Kout)
{
    int idx = blockIdx.x * 256 + threadIdx.x;
    if (idx >= rows * Kout) return;
    int r = idx / Kout, k = idx - r * Kout;
    out[idx] = (k < Kin) ? f2bf(in[(size_t)r * Kin + k]) : 0;
}

// melW [80][1024] f32 -> [128][1024] bf16 (rows 80..127 zero)
__global__ void cvt_melw(const float* __restrict__ in, unsigned short* __restrict__ out)
{
    int idx = blockIdx.x * 256 + threadIdx.x;
    if (idx >= 128 * 1024) return;
    int r = idx >> 10, k = idx & 1023;
    out[idx] = (r < 80) ? f2bf(in[(size_t)r * 1024 + k]) : 0;
}

__global__ void cvt_w1(const float* __restrict__ W, unsigned short* __restrict__ out)
{
    int idx = blockIdx.x * 256 + threadIdx.x;
    if (idx >= 3072 * 608) return;
    int n = idx / 608, k = idx - n * 608;
    int orig = (n < 1024) ? n : n + 1024;
    out[idx] = (k < 592) ? f2bf(W[(size_t)orig * 592 + k]) : 0;
}

__global__ void cvt_w2(const float* __restrict__ W, unsigned short* __restrict__ out)
{
    int idx = blockIdx.x * 256 + threadIdx.x;
    if (idx >= 3072 * 1024) return;
    int n = idx >> 10, k = idx & 1023;
    int orig = (n < 1024) ? n : n + 1024;
    out[idx] = f2bf(W[(size_t)orig * 1024 + k]);
}

__global__ void decin_k2(const float* __restrict__ mel, unsigned short* __restrict__ din,
                         unsigned short* __restrict__ xcat)
{
    int idx = blockIdx.x * 256 + threadIdx.x;
    if (idx >= B_ * T_ * 96) return;
    int r = idx / 96, j = idx - r * 96;
    int b = r / T_, t = r - b * T_;
    float v = (j < M_ && t > 0) ? mel[((size_t)b * T_ + t - 1) * M_ + j] : 0.f;
    unsigned short bv = f2bf(v);
    din[(size_t)r * 96 + j] = bv;
    xcat[(size_t)r * 608 + 512 + j] = bv;
}

// cell for both decoder layers: gates fp32 [rows][3072] = [i;g;o], out bf16
__global__ void dec_cell1(const float* __restrict__ g, const float* __restrict__ b1,
                          unsigned short* __restrict__ h, int rows)
{
    int idx = blockIdx.x * 256 + threadIdx.x;
    if (idx >= rows * H_) return;
    int r = idx >> 10, j = idx & 1023;
    const float* gr = g + (size_t)r * 3072;
    float ig = sigf(gr[j] + b1[j]);
    float gg = tanhfast(gr[1024 + j] + b1[2048 + j]);
    float og = sigf(gr[2048 + j] + b1[3072 + j]);
    h[idx] = f2bf(og * tanhfast(ig * gg));
}

__global__ __launch_bounds__(256) void stop_head(
    const unsigned short* __restrict__ h2, const float* __restrict__ sw,
    const float* __restrict__ sb, float* __restrict__ out)
{
    int row = blockIdx.x * 4 + (threadIdx.x >> 6);
    int lane = threadIdx.x & 63;
    const unsigned short* hr = h2 + (size_t)row * H_;
    float acc = 0.f;
#pragma unroll
    for (int i = 0; i < H_; i += 64) acc += bf2f(hr[i + lane]) * sw[i + lane];
    for (int off = 32; off; off >>= 1) acc += __shfl_xor(acc, off);
    if (lane == 0) out[row] = acc + sb[0];
}

// ---------------- persistent LSTM: 2 blocks/direction, tagged-word sync ----
// Cross-block h exchange: each thread stores ONE 64-bit word {tag=step+1,
// 2xf16 h} (relaxed agent scope -> sc1, straight to LLC, no cache maint).
// Partner threads spin-load their word until the tag matches. Double-buffered
// by step parity (skew<=1 proof: a block writes slot s only after consuming
// partner's previous write to s). MFMA is split own-k / partner-k so the LLC
// propagate hides under the own-k MFMA.
__global__ __launch_bounds__(1024, 4) void lstm_persist5(
    const float* __restrict__ gi_f, const float* __restrict__ gi_b,
    const float* __restrict__ Wf, const float* __restrict__ Wb,
    _Float16* __restrict__ hist,               // [2][16][256][256] f16
    unsigned long long* __restrict__ hstage)   // [2 slots][2 dir][2 half][8 ba][128 hid]
{
    const int blk = blockIdx.x;
    const int dir = blk >> 1, half = blk & 1;
    const float* gi = dir ? gi_b : gi_f;
    const float* W  = dir ? Wb : Wf;
    const int tid = threadIdx.x, wid = tid >> 6, lane = tid & 63;
    const int l15 = lane & 15, q = lane >> 4;
    const int half4 = half * 4, ph4 = (half ^ 1) * 4;

    __shared__ _Float16 h_lds[16][264];
    __shared__ float exch[512][17];

    // --- preload W fragments, split by own/partner k-range ---
    half8 wOA[4], wPA[4], wOB[4], wPB[4];
    {
        const int gt0 = wid >> 3, hb0 = wid & 7;
        const int gt1 = (wid + 16) >> 3;
        const float* wr0 = W + (size_t)(gt0 * 256 + half * 128 + hb0 * 16 + l15) * 256;
        const float* wr1 = W + (size_t)(gt1 * 256 + half * 128 + hb0 * 16 + l15) * 256;
#pragma unroll
        for (int i = 0; i < 4; ++i) {
            const int kO = (half4 + i) * 32 + q * 8;
            const int kP = (ph4 + i) * 32 + q * 8;
            half8 a, b, c, d;
#pragma unroll
            for (int j = 0; j < 8; ++j) {
                a[j] = (_Float16)wr0[kO + j];
                b[j] = (_Float16)wr0[kP + j];
                c[j] = (_Float16)wr1[kO + j];
                d[j] = (_Float16)wr1[kP + j];
            }
            wOA[i] = a; wPA[i] = b; wOB[i] = c; wPB[i] = d;
        }
    }
    for (int i = tid; i < 16 * 264; i += 1024) ((_Float16*)h_lds)[i] = (_Float16)0.f;
    for (int i = tid; i < 512 * 17; i += 1024) ((float*)exch)[i] = 0.f;

    const int hid = tid & 127;
    const int ba  = tid >> 7;       // 0..7
    const int bb  = ba + 8;
    const int gh  = half * 128 + hid;
    float c0 = 0.f, c1 = 0.f;

    const int exr0 = (wid >> 3) * 128 + (wid & 7) * 16 + l15;
    const int exr1 = ((wid + 16) >> 3) * 128 + (wid & 7) * 16 + l15;

    // own tagged-word index pieces (slot added per step)
    const int own_base = ((dir * 2 + half) * 8 + ba) * 128 + hid;
    const int par_base = ((dir * 2 + (half ^ 1)) * 8 + ba) * 128 + hid;
    const int pc = (half ^ 1) * 128 + hid;      // partner column this thread fills

    // gi prefetch for step 0
    float gp0[4], gp1[4];
    {
        const int s0 = dir ? 255 : 0;
        const float* g0 = gi + ((size_t)s0 * 16 + ba) * 1024 + gh;
        const float* g1 = gi + ((size_t)s0 * 16 + bb) * 1024 + gh;
#pragma unroll
        for (int g2 = 0; g2 < 4; ++g2) { gp0[g2] = g0[g2 * 256]; gp1[g2] = g1[g2 * 256]; }
    }
    __syncthreads();

    for (int step = 0; step < 256; ++step) {
        const int s = dir ? (255 - step) : step;

        // ---- update: h(step) from exch (= Whh@h(step-1)) + gi ----
        float h0, h1;
        {
            float xi = exch[hid][ba] + gp0[0];
            float xf = exch[128 + hid][ba] + gp0[1];
            float xg = exch[256 + hid][ba] + gp0[2];
            float xo = exch[384 + hid][ba] + gp0[3];
            float ig = sigf(xi), fg = sigf(xf), gg = tanhfast(xg), og = sigf(xo);
            c0 = fg * c0 + ig * gg; h0 = og * tanhfast(c0);
            xi = exch[hid][bb] + gp1[0];
            xf = exch[128 + hid][bb] + gp1[1];
            xg = exch[256 + hid][bb] + gp1[2];
            xo = exch[384 + hid][bb] + gp1[3];
            ig = sigf(xi); fg = sigf(xf); gg = tanhfast(xg); og = sigf(xo);
            c1 = fg * c1 + ig * gg; h1 = og * tanhfast(c1);
        }
        // own h -> LDS + tagged word to LLC + history + next-gi prefetch
        h_lds[ba][gh] = (_Float16)h0;
        h_lds[bb][gh] = (_Float16)h1;
        {
            unsigned int d32 = (unsigned int)h2u((_Float16)h0) |
                               ((unsigned int)h2u((_Float16)h1) << 16);
            unsigned long long wv = ((unsigned long long)(unsigned int)(step + 1) << 32) | d32;
            __hip_atomic_store(&hstage[(step & 1) * 4096 + own_base], wv,
                               __ATOMIC_RELAXED, __HIP_MEMORY_SCOPE_AGENT);
        }
        hist[(((size_t)(dir * 16 + ba) * 256 + s) * 256) + gh] = (_Float16)h0;
        hist[(((size_t)(dir * 16 + bb) * 256 + s) * 256) + gh] = (_Float16)h1;
        if (step < 255) {
            const int s2 = dir ? (254 - step) : (step + 1);
            const float* g0 = gi + ((size_t)s2 * 16 + ba) * 1024 + gh;
            const float* g1 = gi + ((size_t)s2 * 16 + bb) * 1024 + gh;
#pragma unroll
            for (int g2 = 0; g2 < 4; ++g2) { gp0[g2] = g0[g2 * 256]; gp1[g2] = g1[g2 * 256]; }
        }
        __syncthreads();   // own-half h_lds complete

        if (step < 255) {
            // ---- MFMA over own k-range (hides LLC propagate) ----
            f32x4 acc0 = (f32x4){0.f, 0.f, 0.f, 0.f};
            f32x4 acc1 = (f32x4){0.f, 0.f, 0.f, 0.f};
            const _Float16* hrow = &h_lds[l15][0];
#pragma unroll
            for (int i = 0; i < 4; ++i) {
                half8 a = *(const half8*)(hrow + (half4 + i) * 32 + q * 8);
                acc0 = __builtin_amdgcn_mfma_f32_16x16x32_f16(a, wOA[i], acc0, 0, 0, 0);
                acc1 = __builtin_amdgcn_mfma_f32_16x16x32_f16(a, wOB[i], acc1, 0, 0, 0);
            }
            // ---- spin on partner tagged word; fill partner half of h_lds ----
            {
                unsigned long long pv;
                const unsigned int want = (unsigned int)(step + 1);
                do {
                    pv = __hip_atomic_load(&hstage[(step & 1) * 4096 + par_base],
                                           __ATOMIC_RELAXED, __HIP_MEMORY_SCOPE_AGENT);
                } while ((unsigned int)(pv >> 32) != want);
                unsigned int d32 = (unsigned int)pv;
                *(unsigned short*)&h_lds[ba][pc] = (unsigned short)(d32 & 0xFFFF);
                *(unsigned short*)&h_lds[bb][pc] = (unsigned short)(d32 >> 16);
            }
            __syncthreads();   // partner half complete
            // ---- MFMA over partner k-range ----
#pragma unroll
            for (int i = 0; i < 4; ++i) {
                half8 a = *(const half8*)(hrow + (ph4 + i) * 32 + q * 8);
                acc0 = __builtin_amdgcn_mfma_f32_16x16x32_f16(a, wPA[i], acc0, 0, 0, 0);
                acc1 = __builtin_amdgcn_mfma_f32_16x16x32_f16(a, wPB[i], acc1, 0, 0, 0);
            }
            *(f32x4*)&exch[exr0][q * 4] = acc0;
            *(f32x4*)&exch[exr1][q * 4] = acc1;
            __syncthreads();   // exch ready for next update
        }
    }
}

// ---------------- host orchestration --------------------------------------
static inline void launch_mfma(hipStream_t st, const unsigned short* A, const unsigned short* B,
                               void* C, const float* bias, int M, int N, int K, int ldc, int epi = 0,
                               const float* cb = nullptr, const float* gam = nullptr,
                               const float* bet = nullptr, const float* mu = nullptr,
                               const float* va = nullptr)
{
    dim3 grid(N / 128, M / 128);
    gemm_mfma<<<grid, 256, 0, st>>>(A, B, C, bias, M, N, K, ldc, epi, cb, gam, bet, mu, va);
}

extern "C" void kernel_launch(void* const* d_in, const int* in_sizes, int n_in,
                              void* d_out, int out_size, void* d_ws, size_t ws_size,
                              hipStream_t stream)
{
    const int*   text   = (const int*)d_in[0];
    const float* mel_t  = (const float*)d_in[1];
    const float* emb    = (const float*)d_in[2];
    const float* conv_w = (const float*)d_in[3];
    const float* conv_b = (const float*)d_in[4];
    const float* bn_g   = (const float*)d_in[5];
    const float* bn_b   = (const float*)d_in[6];
    const float* bn_m   = (const float*)d_in[7];
    const float* bn_v   = (const float*)d_in[8];
    const float* Wih_f  = (const float*)d_in[9];
    const float* Whh_f  = (const float*)d_in[10];
    const float* b_f    = (const float*)d_in[11];
    const float* Wih_b  = (const float*)d_in[12];
    const float* Whh_b  = (const float*)d_in[13];
    const float* b_b    = (const float*)d_in[14];
    const float* Wq     = (const float*)d_in[15];
    const float* bq     = (const float*)d_in[16];
    const float* Wk     = (const float*)d_in[17];
    const float* bk     = (const float*)d_in[18];
    const float* Wv     = (const float*)d_in[19];
    const float* bv     = (const float*)d_in[20];
    const float* Wo     = (const float*)d_in[21];
    const float* bo     = (const float*)d_in[22];
    const float* Wih1   = (const float*)d_in[23];
    const float* b1     = (const float*)d_in[24];
    const float* Wih2   = (const float*)d_in[25];
    const float* b2     = (const float*)d_in[26];
    const float* melW   = (const float*)d_in[27];
    const float* melb   = (const float*)d_in[28];
    const float* stopW  = (const float*)d_in[29];
    const float* stopb  = (const float*)d_in[30];
    float* out = (float*)d_out;
    (void)in_sizes; (void)n_in; (void)out_size; (void)ws_size;

    float* ws = (float*)d_ws;
    float* big  = ws;                       // 13107200 f: im2col | scores fp32 | h2b
    float* pool = ws + 13107200;

    unsigned long long* hstage = (unsigned long long*)(ws + 6000000); // 8192 words, 64KB

    // phase A/B (encoder)
    float*          gi_f   = pool + 0;
    float*          gi_b   = pool + 4194304;
    unsigned short* enc_bf = (unsigned short*)(pool + 8388608);
    float*          P0     = pool + 9437184;
    float*          P1     = pool + 11534336;
    unsigned short* xsT    = (unsigned short*)(pool + 13631488);
    _Float16*       hist   = (_Float16*)(pool + 14155776);     // 4MB f16
    // phase C (attention)
    unsigned short* kbf    = (unsigned short*)(pool + 0);
    unsigned short* vT     = (unsigned short*)(pool + 1048576);
    unsigned short* qbf    = (unsigned short*)(pool + 2097152);
    unsigned short* probs  = (unsigned short*)(pool + 9437184);
    unsigned short* dinb   = (unsigned short*)(pool + 16008192);
    unsigned short* ctxb   = (unsigned short*)(pool + 16622592);
    // phase D (decoder)
    float*          gates  = pool + 0;
    unsigned short* h1b    = (unsigned short*)(pool + 9830400);
    unsigned short* xcat   = (unsigned short*)(pool + 19899392);
    // weights
    float*          WB     = pool + 23790592;
    unsigned short* cWc  = (unsigned short*)(WB + 0);
    unsigned short* cWif = (unsigned short*)(WB + 1966080);
    unsigned short* cWib = (unsigned short*)(WB + 2228224);
    unsigned short* cWk  = (unsigned short*)(WB + 2490368);
    unsigned short* cWv  = (unsigned short*)(WB + 2621440);
    unsigned short* cWq  = (unsigned short*)(WB + 2752512);
    unsigned short* cWo  = (unsigned short*)(WB + 2777088);
    unsigned short* cW1  = (unsigned short*)(WB + 2908160);
    unsigned short* cW2  = (unsigned short*)(WB + 3842048);
    unsigned short* cWm  = (unsigned short*)(WB + 5414912);   // 128x1024 bf16

    auto ceil256 = [](int n) { return (n + 255) / 256; };

    // zero tagged-word staging (tags must start != 1..256)
    hipMemsetAsync(hstage, 0, 8192 * 8, stream);

    // ---- weight conversions ----
    cvt_bf<<<ceil256(1536 * 2560), 256, 0, stream>>>(conv_w, cWc, 1536, 2560, 2560);
    cvt_bf<<<ceil256(1024 * 512), 256, 0, stream>>>(Wih_f, cWif, 1024, 512, 512);
    cvt_bf<<<ceil256(1024 * 512), 256, 0, stream>>>(Wih_b, cWib, 1024, 512, 512);
    cvt_bf<<<ceil256(512 * 512), 256, 0, stream>>>(Wk, cWk, 512, 512, 512);
    cvt_bf<<<ceil256(512 * 512), 256, 0, stream>>>(Wv, cWv, 512, 512, 512);
    cvt_bf<<<ceil256(512 * 96), 256, 0, stream>>>(Wq, cWq, 512, 80, 96);
    cvt_bf<<<ceil256(512 * 512), 256, 0, stream>>>(Wo, cWo, 512, 512, 512);
    cvt_w1<<<ceil256(3072 * 608), 256, 0, stream>>>(Wih1, cW1);
    cvt_w2<<<ceil256(3072 * 1024), 256, 0, stream>>>(Wih2, cW2);
    cvt_melw<<<ceil256(128 * 1024), 256, 0, stream>>>(melW, cWm);

    // ---- encoder: embedding + 3 convs ----
    embed_k<<<ceil256(B_ * S_ * D_), 256, 0, stream>>>(text, emb, P0);
    float* cin = P0;
    float* cout = P1;
    for (int l = 0; l < 3; ++l) {
        im2col_bf<<<ceil256(B_ * S_ * 2560), 256, 0, stream>>>(cin, (unsigned short*)big);
        launch_mfma(stream, (unsigned short*)big, cWc + (size_t)l * 512 * 2560,
                    cout, nullptr, B_ * S_, 512, 2560, 512, 1,
                    conv_b + l * 512, bn_g + l * 512, bn_b + l * 512, bn_m + l * 512, bn_v + l * 512);
        float* tmp = cin; cin = cout; cout = tmp;
    }
    transp_bf<<<ceil256(B_ * S_ * D_), 256, 0, stream>>>(cin, xsT);

    // ---- encoder LSTM ----
    launch_mfma(stream, xsT, cWif, gi_f, b_f, S_ * B_, 1024, 512, 1024);
    launch_mfma(stream, xsT, cWib, gi_b, b_b, S_ * B_, 1024, 512, 1024);
    lstm_persist5<<<4, 1024, 0, stream>>>(gi_f, gi_b, Whh_f, Whh_b, hist, hstage);
    hist2enc<<<ceil256(B_ * S_ * D_), 256, 0, stream>>>(hist, enc_bf);

    // ---- attention projections ----
    launch_mfma(stream, enc_bf, cWk, kbf, bk, B_ * S_, 512, 512, 512, 2);
    launch_mfma(stream, enc_bf, cWv, vT, bv, B_ * S_, 512, 512, 0, 3);
    decin_k2<<<ceil256(B_ * T_ * 96), 256, 0, stream>>>(mel_t, dinb, xcat);
    launch_mfma(stream, dinb, cWq, qbf, bq, B_ * T_, 512, 96, 512, 2);

    // ---- attention ----
    attn_qk<<<dim3(2, 7, 64), 256, 0, stream>>>(qbf, kbf, big);
    attn_sm<<<12800, 256, 0, stream>>>(big, probs);
    attn_pv<<<dim3(1, 7, 64), 256, 0, stream>>>(probs, vT, ctxb);

    // ---- Wo projection -> xcat[:, 0:512) bf16 ----
    launch_mfma(stream, ctxb, cWo, xcat, bo, B_ * T_, 512, 512, 608, 2);

    // ---- decoder cells (f-gate dropped; N=3072 = [i;g;o]) ----
    unsigned short* h2b = (unsigned short*)big;
    const int MC = 3200;
    for (int c0 = 0; c0 < B_ * T_; c0 += MC) {
        launch_mfma(stream, xcat + (size_t)c0 * 608, cW1, gates, nullptr, MC, 3072, 608, 3072);
        dec_cell1<<<ceil256(MC * H_), 256, 0, stream>>>(gates, b1, h1b + (size_t)c0 * H_, MC);
    }
    for (int c0 = 0; c0 < B_ * T_; c0 += MC) {
        launch_mfma(stream, h1b + (size_t)c0 * H_, cW2, gates, nullptr, MC, 3072, 1024, 3072);
        dec_cell1<<<ceil256(MC * H_), 256, 0, stream>>>(gates, b2, h2b + (size_t)c0 * H_, MC);
    }

    // ---- output heads (mel via MFMA, stop via reduction) ----
    launch_mfma(stream, h2b, cWm, out, melb, B_ * T_, 128, 1024, 80, 4);
    stop_head<<<(B_ * T_) / 4, 256, 0, stream>>>(h2b, stopW, stopb, out + (size_t)B_ * T_ * M_);
}